// Round 9
// baseline (1176.806 us; speedup 1.0000x reference)
//
#include <hip/hip_runtime.h>
#include <hip/hip_bf16.h>
#include <hip/hip_cooperative_groups.h>

namespace cg = cooperative_groups;

#define N_NODES 50000
#define N_EDGES 1600000
#define HEADS 8
#define HDIM 16
#define D1 128   // HEADS*HDIM
#define NEG_SLOPE 0.2f
#define SCAN_BLKS 196  // ceil(50000/256)
#define RTILES 3125    // 50000/16
#define GTASKS 1564    // 782 x-groups * 2 c-groups
#define ATASKS 12500   // 50000/4 node groups

typedef short short8 __attribute__((ext_vector_type(8)));
typedef float f32x4 __attribute__((ext_vector_type(4)));
typedef _Float16 half2v __attribute__((ext_vector_type(2)));

// ---- dtype helpers (isf32: 1 = buffers are fp32, 0 = bf16) ----
__device__ __forceinline__ float bf2f(ushort u) {
    union { unsigned u; float f; } x; x.u = ((unsigned)u) << 16; return x.f;
}
__device__ __forceinline__ ushort f2bf(float f) {
    union { float f; unsigned u; } x; x.f = f;
    unsigned r = x.u + 0x7FFF + ((x.u >> 16) & 1);   // RNE
    return (ushort)(r >> 16);
}
__device__ __forceinline__ float ldf(const void* p, size_t i, int isf32) {
    return isf32 ? ((const float*)p)[i] : bf2f(((const ushort*)p)[i]);
}
__device__ __forceinline__ void splitbf(float f, ushort& hi, ushort& lo) {
    unsigned u = __float_as_uint(f);
    unsigned uh = u & 0xFFFF0000u;
    hi = (ushort)(uh >> 16);
    lo = f2bf(f - __uint_as_float(uh));
}

// ---------------- workspace layout (bytes) ----------------
#define O_ROWPTR   0
#define O_DEG      200064
#define O_BSUM     400128
#define O_TMPSCAN  408320
#define O_FLAGS    608384
#define O_POS      608640
#define O_ESRC     7008640
#define O_W1HI     13408640
#define O_W1LO     13556096
#define O_W2HI     13703552
#define O_W2LO     13777280
#define O_B1F      13851008
#define O_B2F      13851520
#define O_FEATG    13852032
#define O_EL       26652032
#define O_ER       28252032
#define O_A2HI     29852032
#define O_A2LO     42652032

// ================= device phase helpers (shared by fused + fallback) =================

__device__ __forceinline__ void detect_body(const ushort* w1, int* flags, int* sm) {
    int t = threadIdx.x;
    int cnt = 0;
    for (int i = t; i < 32768; i += 256) {
        int e = (w1[i] >> 7) & 0xFF;
        if (e >= 0xC8) cnt++;
    }
    sm[t] = cnt; __syncthreads();
    for (int off = 128; off > 0; off >>= 1) {
        if (t < off) sm[t] += sm[t + off];
        __syncthreads();
    }
    if (t == 0) flags[0] = (sm[0] > 0) ? 1 : 0;
}

__device__ __forceinline__ void count_elem(const int4* dst4, int* deg, int4* pos4, int i) {
    int4 d = dst4[i];
    int4 p;
    p.x = atomicAdd(&deg[d.x], 1);
    p.y = atomicAdd(&deg[d.y], 1);
    p.z = atomicAdd(&deg[d.z], 1);
    p.w = atomicAdd(&deg[d.w], 1);
    pos4[i] = p;
}

__device__ __forceinline__ void place_elem(const int4* src4, const int4* dst4,
                                           const int* rowptr, const int4* pos4, int* esrc, int i) {
    int4 s = src4[i], d = dst4[i], p = pos4[i];
    esrc[rowptr[d.x] + p.x] = s.x;
    esrc[rowptr[d.y] + p.y] = s.y;
    esrc[rowptr[d.z] + p.z] = s.z;
    esrc[rowptr[d.w] + p.w] = s.w;
}

__device__ __forceinline__ void scan1_body(const int* deg, int* tmp, int* bsum, int b, int* sm) {
    int t = threadIdx.x;
    int i = b * 256 + t;
    int x = (i < N_NODES) ? deg[i] : 0;
    sm[t] = x; __syncthreads();
    for (int off = 1; off < 256; off <<= 1) {
        int v = (t >= off) ? sm[t - off] : 0;
        __syncthreads();
        sm[t] += v;
        __syncthreads();
    }
    if (i < N_NODES) tmp[i] = sm[t];
    if (t == 255) bsum[b] = sm[255];
}

__device__ __forceinline__ void scan23_body(const int* tmp, const int* bsum, int* rowptr, int b, int* sm) {
    int t = threadIdx.x;
    int x = (t < SCAN_BLKS) ? bsum[t] : 0;
    sm[t] = x; __syncthreads();
    for (int off = 1; off < 256; off <<= 1) {
        int v = (t >= off) ? sm[t - off] : 0;
        __syncthreads();
        sm[t] += v;
        __syncthreads();
    }
    int boff = sm[b] - ((b < SCAN_BLKS) ? bsum[b] : 0);  // exclusive prefix of this chunk
    int i = b * 256 + t;
    if (i < N_NODES) rowptr[i + 1] = tmp[i] + boff;
    if (i == 0) rowptr[0] = 0;
}

// prep unit u in [0,217): 0..143 -> W1 rows; 144..215 -> W2 rows; 216 -> biases
__device__ __forceinline__ void wprep_elem(const void* W, const void* al, const void* ar,
                                           int K, int kshift, ushort* whi, ushort* wlo,
                                           int isf32, int idx) {
    if (idx >= 144 * K) return;
    int n = idx >> kshift, k = idx & (K - 1);
    float f;
    if (n < 128) {
        f = ldf(W, (size_t)k * 128 + n, isf32);
    } else if (n < 136) {
        int h = n - 128;
        f = 0.f;
#pragma unroll
        for (int d = 0; d < HDIM; ++d)
            f = fmaf(ldf(W, (size_t)k * 128 + h * 16 + d, isf32), ldf(al, h * 16 + d, isf32), f);
    } else {
        int h = n - 136;
        f = 0.f;
#pragma unroll
        for (int d = 0; d < HDIM; ++d)
            f = fmaf(ldf(W, (size_t)k * 128 + h * 16 + d, isf32), ldf(ar, h * 16 + d, isf32), f);
    }
    ushort hi = f2bf(f);
    wlo[n * K + k] = f2bf(f - bf2f(hi));
    whi[n * K + k] = hi;
}

__device__ __forceinline__ void prep_unit(int u, int isf32,
                                          const void* W1, const void* al1, const void* ar1, const void* b1,
                                          const void* W2, const void* al2, const void* ar2, const void* b2,
                                          ushort* w1hi, ushort* w1lo, ushort* w2hi, ushort* w2lo,
                                          float* b1f, float* b2f) {
    int t = threadIdx.x;
    if (u < 144) {
        wprep_elem(W1, al1, ar1, 256, 8, w1hi, w1lo, isf32, u * 256 + t);
    } else if (u < 216) {
        wprep_elem(W2, al2, ar2, 128, 7, w2hi, w2lo, isf32, (u - 144) * 256 + t);
    } else {
        if (t < 128) b1f[t] = ldf(b1, t, isf32);
        else b2f[t - 128] = ldf(b2, t - 128, isf32);
    }
}

// coalesced featg tile store via per-wave LDS region (16x72 fp16, 16B-aligned rows)
__device__ __forceinline__ void store_tile(_Float16 (*sfe)[72], _Float16* featg,
                                           const f32x4* acc, int lane, int quad, int l16,
                                           int rowb0, int cbase) {
#pragma unroll
    for (int ci = 0; ci < 4; ++ci)
#pragma unroll
        for (int r = 0; r < 4; ++r)
            sfe[quad * 4 + r][ci * 16 + l16] = (_Float16)acc[ci][r];
    int rr = lane >> 3, ch = lane & 7;
#pragma unroll
    for (int s = 0; s < 2; ++s) {
        int row = s * 8 + rr;
        short8 v = *(const short8*)&sfe[row][ch * 8];
        *(short8*)(featg + (size_t)(rowb0 + row) * D1 + cbase * 16 + ch * 8) = v;
    }
}

// one wave's gemm1 task: 16-row panel rt, c-group cbase (0 or 4; cbase==4 also does el/er tile)
__device__ __forceinline__ void gemm1_wave(const void* A, const ushort* Bhi, const ushort* Blo,
                                           _Float16* featg, float* el, float* er,
                                           int isf32, int rt, int cbase, int lane,
                                           _Float16 (*sfe)[72]) {
    int quad = lane >> 4, l16 = lane & 15;
    const int K = 256;
    size_t a_off = (size_t)(rt * 16 + l16) * K + quad * 8;
    int rowb0 = rt * 16;

    short8 ahi[8], alo[8];
    if (isf32) {
        const float* ap = (const float*)A + a_off;
#pragma unroll
        for (int i = 0; i < 8; ++i) {
            f32x4 u0 = *(const f32x4*)(ap + 32 * i);
            f32x4 u1 = *(const f32x4*)(ap + 32 * i + 4);
            float a8[8] = {u0[0], u0[1], u0[2], u0[3], u1[0], u1[1], u1[2], u1[3]};
#pragma unroll
            for (int j = 0; j < 8; ++j) {
                ushort h, l;
                splitbf(a8[j], h, l);
                ahi[i][j] = (short)h; alo[i][j] = (short)l;
            }
        }
    } else {
        const ushort* ap = (const ushort*)A + a_off;
#pragma unroll
        for (int i = 0; i < 8; ++i) ahi[i] = *(const short8*)(ap + 32 * i);
    }

    f32x4 acc[4];
#pragma unroll
    for (int ci = 0; ci < 4; ++ci) acc[ci] = (f32x4){0.f, 0.f, 0.f, 0.f};
#pragma unroll
    for (int ci = 0; ci < 4; ++ci) {
        int c = cbase + ci;
        const ushort* bh = Bhi + (size_t)(c * 16 + l16) * K + quad * 8;
        if (isf32) {
            const ushort* bl = Blo + (size_t)(c * 16 + l16) * K + quad * 8;
#pragma unroll
            for (int k = 0; k < 8; ++k) {
                short8 bh8 = *(const short8*)(bh + 32 * k);
                short8 bl8 = *(const short8*)(bl + 32 * k);
                acc[ci] = __builtin_amdgcn_mfma_f32_16x16x32_bf16(ahi[k], bh8, acc[ci], 0, 0, 0);
                acc[ci] = __builtin_amdgcn_mfma_f32_16x16x32_bf16(ahi[k], bl8, acc[ci], 0, 0, 0);
                acc[ci] = __builtin_amdgcn_mfma_f32_16x16x32_bf16(alo[k], bh8, acc[ci], 0, 0, 0);
            }
        } else {
#pragma unroll
            for (int k = 0; k < 8; ++k) {
                short8 bh8 = *(const short8*)(bh + 32 * k);
                acc[ci] = __builtin_amdgcn_mfma_f32_16x16x32_bf16(ahi[k], bh8, acc[ci], 0, 0, 0);
            }
        }
    }
    store_tile(sfe, featg, acc, lane, quad, l16, rowb0, cbase);

    if (cbase == 4) {
        const ushort* bh = Bhi + (size_t)(8 * 16 + l16) * K + quad * 8;
        const ushort* bl = Blo + (size_t)(8 * 16 + l16) * K + quad * 8;
        f32x4 a = {0.f, 0.f, 0.f, 0.f};
#pragma unroll
        for (int k = 0; k < 8; ++k) {
            short8 bh8 = *(const short8*)(bh + 32 * k);
            short8 bl8 = *(const short8*)(bl + 32 * k);
            a = __builtin_amdgcn_mfma_f32_16x16x32_bf16(ahi[k], bh8, a, 0, 0, 0);
            a = __builtin_amdgcn_mfma_f32_16x16x32_bf16(ahi[k], bl8, a, 0, 0, 0);
            if (isf32) a = __builtin_amdgcn_mfma_f32_16x16x32_bf16(alo[k], bh8, a, 0, 0, 0);
        }
#pragma unroll
        for (int r = 0; r < 4; ++r) {
            int row = rowb0 + quad * 4 + r;
            if (l16 < 8) el[row * 8 + l16] = a[r];
            else         er[row * 8 + (l16 - 8)] = a[r];
        }
    }
}

__device__ __forceinline__ void gemm2_wave(const ushort* a2hi, const ushort* a2lo,
                                           const ushort* Bhi, const ushort* Blo,
                                           _Float16* featg, float* el, float* er,
                                           int isf32, int rt, int cbase, int lane,
                                           _Float16 (*sfe)[72]) {
    int quad = lane >> 4, l16 = lane & 15;
    const int K = 128;
    size_t a_off = (size_t)(rt * 16 + l16) * K + quad * 8;
    int rowb0 = rt * 16;

    short8 ahi[4], alo[4];
#pragma unroll
    for (int i = 0; i < 4; ++i) ahi[i] = *(const short8*)(a2hi + a_off + 32 * i);
#pragma unroll
    for (int i = 0; i < 4; ++i) alo[i] = *(const short8*)(a2lo + a_off + 32 * i);

    f32x4 acc[4];
#pragma unroll
    for (int ci = 0; ci < 4; ++ci) acc[ci] = (f32x4){0.f, 0.f, 0.f, 0.f};
#pragma unroll
    for (int ci = 0; ci < 4; ++ci) {
        int c = cbase + ci;
        const ushort* bh = Bhi + (size_t)(c * 16 + l16) * K + quad * 8;
        const ushort* bl = Blo + (size_t)(c * 16 + l16) * K + quad * 8;
#pragma unroll
        for (int k = 0; k < 4; ++k) {
            short8 bh8 = *(const short8*)(bh + 32 * k);
            acc[ci] = __builtin_amdgcn_mfma_f32_16x16x32_bf16(ahi[k], bh8, acc[ci], 0, 0, 0);
            acc[ci] = __builtin_amdgcn_mfma_f32_16x16x32_bf16(alo[k], bh8, acc[ci], 0, 0, 0);
            if (isf32) {
                short8 bl8 = *(const short8*)(bl + 32 * k);
                acc[ci] = __builtin_amdgcn_mfma_f32_16x16x32_bf16(ahi[k], bl8, acc[ci], 0, 0, 0);
            }
        }
    }
    store_tile(sfe, featg, acc, lane, quad, l16, rowb0, cbase);

    if (cbase == 4) {
        const ushort* bh = Bhi + (size_t)(8 * 16 + l16) * K + quad * 8;
        const ushort* bl = Blo + (size_t)(8 * 16 + l16) * K + quad * 8;
        f32x4 a = {0.f, 0.f, 0.f, 0.f};
#pragma unroll
        for (int k = 0; k < 4; ++k) {
            short8 bh8 = *(const short8*)(bh + 32 * k);
            short8 bl8 = *(const short8*)(bl + 32 * k);
            a = __builtin_amdgcn_mfma_f32_16x16x32_bf16(ahi[k], bh8, a, 0, 0, 0);
            a = __builtin_amdgcn_mfma_f32_16x16x32_bf16(ahi[k], bl8, a, 0, 0, 0);
            a = __builtin_amdgcn_mfma_f32_16x16x32_bf16(alo[k], bh8, a, 0, 0, 0);
        }
#pragma unroll
        for (int r = 0; r < 4; ++r) {
            int row = rowb0 + quad * 4 + r;
            if (l16 < 8) el[row * 8 + l16] = a[r];
            else         er[row * 8 + (l16 - 8)] = a[r];
        }
    }
}

// one wave's aggregation of node v (batch-8 edges)
__device__ __forceinline__ void agg_node(const int* rowptr, const int* esrc, const half2v* featg,
                                         const float* el, const float* er, const float* bias,
                                         void* out, unsigned* olo, int mode, int isf32,
                                         int v, int lane) {
    int h8 = lane & 7;
    int esel = lane >> 3;
    float erv = er[v * 8 + h8];
    int beg = rowptr[v], end = rowptr[v + 1];
    int deg = end - beg;
    float acc0 = 0.f, acc1 = 0.f, den = 0.f;
    int jend = beg + (deg & ~7);
    for (int j = beg; j < jend; j += 8) {
        int sv = esrc[j + h8];
        int se = __shfl(sv, esel);
        float x = el[se * 8 + h8] + erv;
        x = x > 0.f ? x : NEG_SLOPE * x;
        float w = __expf(x);
        int s_[8];
#pragma unroll
        for (int e = 0; e < 8; ++e) s_[e] = __shfl(sv, e);
        half2v hh_[8];
#pragma unroll
        for (int e = 0; e < 8; ++e) hh_[e] = featg[(size_t)s_[e] * 64 + lane];
        float we_[8];
#pragma unroll
        for (int e = 0; e < 8; ++e) we_[e] = __shfl(w, e * 8 + esel);
#pragma unroll
        for (int e = 0; e < 8; ++e) {
            den += we_[e];
            acc0 = fmaf(we_[e], (float)hh_[e][0], acc0);
            acc1 = fmaf(we_[e], (float)hh_[e][1], acc1);
        }
    }
    int rem = deg & 7;
    if (rem) {
        int idx = jend + h8;
        if (idx >= end) idx = end - 1;
        int sv = esrc[idx];
        int se = __shfl(sv, esel);
        float x = el[se * 8 + h8] + erv;
        x = x > 0.f ? x : NEG_SLOPE * x;
        float w = __expf(x);
        for (int e = 0; e < rem; ++e) {
            float we = __shfl(w, e * 8 + esel);
            int s = __shfl(sv, e);
            half2v hh = featg[(size_t)s * 64 + lane];
            den += we;
            acc0 = fmaf(we, (float)hh[0], acc0);
            acc1 = fmaf(we, (float)hh[1], acc1);
        }
    }
    float inv = (deg > 0) ? 1.0f / den : 0.f;
    float2 bb = ((const float2*)bias)[lane];
    float r0 = fmaf(acc0, inv, bb.x);
    float r1 = fmaf(acc1, inv, bb.y);
    if (mode == 0) {
        r0 = r0 > 0.f ? r0 : (__expf(r0) - 1.f);
        r1 = r1 > 0.f ? r1 : (__expf(r1) - 1.f);
        ushort h0, l0, h1, l1;
        splitbf(r0, h0, l0);
        splitbf(r1, h1, l1);
        ((unsigned*)out)[(size_t)v * 64 + lane] = (unsigned)h0 | ((unsigned)h1 << 16);
        olo[(size_t)v * 64 + lane] = (unsigned)l0 | ((unsigned)l1 << 16);
    } else {
        for (int m = 8; m < 64; m <<= 1) {
            r0 += __shfl_xor(r0, m);
            r1 += __shfl_xor(r1, m);
        }
        if (lane < 8) {
            float v0 = r0 * 0.125f, v1 = r1 * 0.125f;
            if (isf32) {
                float2 st = {v0, v1};
                ((float2*)out)[(size_t)v * 8 + lane] = st;
            } else {
                unsigned pk = (unsigned)f2bf(v0) | ((unsigned)f2bf(v1) << 16);
                ((unsigned*)out)[(size_t)v * 8 + lane] = pk;
            }
        }
    }
}

// ================= fused persistent cooperative kernel =================
__global__ __launch_bounds__(256, 6) void k_fused(const void* A, const int4* src4, const int4* dst4,
                                                  const void* W1, const void* al1, const void* ar1, const void* b1,
                                                  const void* W2, const void* al2, const void* ar2, const void* b2,
                                                  void* dout, char* ws) {
    cg::grid_group grid = cg::this_grid();
    __shared__ __align__(16) char smem[9216];
    int* smi = (int*)smem;
    _Float16 (*sfe)[16][72] = (_Float16(*)[16][72])smem;

    int b = blockIdx.x, t = threadIdx.x, G = gridDim.x;
    int wave = t >> 6, lane = t & 63;

    int* rowptr = (int*)(ws + O_ROWPTR);
    int* deg    = (int*)(ws + O_DEG);
    int* bsum   = (int*)(ws + O_BSUM);
    int* tmpsc  = (int*)(ws + O_TMPSCAN);
    int* flags  = (int*)(ws + O_FLAGS);
    int4* pos4  = (int4*)(ws + O_POS);
    int* esrc   = (int*)(ws + O_ESRC);
    ushort* w1hi = (ushort*)(ws + O_W1HI);
    ushort* w1lo = (ushort*)(ws + O_W1LO);
    ushort* w2hi = (ushort*)(ws + O_W2HI);
    ushort* w2lo = (ushort*)(ws + O_W2LO);
    float* b1f  = (float*)(ws + O_B1F);
    float* b2f  = (float*)(ws + O_B2F);
    _Float16* featg = (_Float16*)(ws + O_FEATG);
    float* el   = (float*)(ws + O_EL);
    float* er   = (float*)(ws + O_ER);
    ushort* a2hi = (ushort*)(ws + O_A2HI);
    ushort* a2lo = (ushort*)(ws + O_A2LO);

    // phase 0: zero deg + dtype detect (block 0)
    for (int i = b * 256 + t; i < N_NODES; i += G * 256) deg[i] = 0;
    if (b == 0) detect_body((const ushort*)W1, flags, smi);
    grid.sync();

    int isf32 = flags[0];

    // phase 1: edge count (atomics) + weight prep (independent)
    for (int i = b * 256 + t; i < N_EDGES / 4; i += G * 256) count_elem(dst4, deg, pos4, i);
    for (int u = b; u < 217; u += G)
        prep_unit(u, isf32, W1, al1, ar1, b1, W2, al2, ar2, b2, w1hi, w1lo, w2hi, w2lo, b1f, b2f);
    grid.sync();

    // phase 2: per-chunk inclusive scan
    if (b < SCAN_BLKS) scan1_body(deg, tmpsc, bsum, b, smi);
    grid.sync();

    // phase 3: chunk-offset scan + rowptr
    if (b < SCAN_BLKS) scan23_body(tmpsc, bsum, rowptr, b, smi);
    grid.sync();

    // phase 4: place (CSR) + gemm1 (independent of CSR)
    for (int i = b * 256 + t; i < N_EDGES / 4; i += G * 256) place_elem(src4, dst4, rowptr, pos4, esrc, i);
    for (int bt = b; bt < GTASKS; bt += G) {
        int rt = (bt >> 1) * 4 + wave;
        int cbase = (bt & 1) * 4;
        if (rt < RTILES)
            gemm1_wave(A, w1hi, w1lo, featg, el, er, isf32, rt, cbase, lane, sfe[wave]);
    }
    grid.sync();

    // phase 5: agg layer 1 -> split-bf16 h
    for (int g = b; g < ATASKS; g += G) {
        int v = g * 4 + wave;
        if (v < N_NODES)
            agg_node(rowptr, esrc, (const half2v*)featg, el, er, b1f, (void*)a2hi, (unsigned*)a2lo, 0, isf32, v, lane);
    }
    grid.sync();

    // phase 6: gemm2
    for (int bt = b; bt < GTASKS; bt += G) {
        int rt = (bt >> 1) * 4 + wave;
        int cbase = (bt & 1) * 4;
        if (rt < RTILES)
            gemm2_wave(a2hi, a2lo, w2hi, w2lo, featg, el, er, isf32, rt, cbase, lane, sfe[wave]);
    }
    grid.sync();

    // phase 7: agg layer 2 -> d_out
    for (int g = b; g < ATASKS; g += G) {
        int v = g * 4 + wave;
        if (v < N_NODES)
            agg_node(rowptr, esrc, (const half2v*)featg, el, er, b2f, dout, nullptr, 1, isf32, v, lane);
    }
}

// ================= fallback multi-kernel path (round-8 structure) =================
__global__ __launch_bounds__(256) void k_detect(const ushort* __restrict__ w1, int* __restrict__ flags) {
    __shared__ int sm[256];
    detect_body(w1, flags, sm);
}
__global__ __launch_bounds__(256) void k_count(const int4* __restrict__ dst4, int* __restrict__ deg,
                                               int4* __restrict__ pos4) {
    int i = blockIdx.x * 256 + threadIdx.x;
    if (i < N_EDGES / 4) count_elem(dst4, deg, pos4, i);
}
__global__ __launch_bounds__(256) void k_scan1(const int* __restrict__ deg, int* __restrict__ tmp,
                                               int* __restrict__ bsum) {
    __shared__ int sm[256];
    scan1_body(deg, tmp, bsum, blockIdx.x, sm);
}
__global__ __launch_bounds__(256) void k_scan23(const int* __restrict__ tmp, const int* __restrict__ bsum,
                                                int* __restrict__ rowptr) {
    __shared__ int sm[256];
    scan23_body(tmp, bsum, rowptr, blockIdx.x, sm);
}
__global__ __launch_bounds__(256) void k_place(const int4* __restrict__ src4, const int4* __restrict__ dst4,
                                               const int* __restrict__ rowptr, const int4* __restrict__ pos4,
                                               int* __restrict__ esrc) {
    int i = blockIdx.x * 256 + threadIdx.x;
    if (i < N_EDGES / 4) place_elem(src4, dst4, rowptr, pos4, esrc, i);
}
__global__ __launch_bounds__(256) void k_prep(const void* W1, const void* al1, const void* ar1, const void* b1,
                                              const void* W2, const void* al2, const void* ar2, const void* b2,
                                              ushort* w1hi, ushort* w1lo, ushort* w2hi, ushort* w2lo,
                                              float* b1f, float* b2f, const int* flags) {
    prep_unit(blockIdx.x, flags[0], W1, al1, ar1, b1, W2, al2, ar2, b2, w1hi, w1lo, w2hi, w2lo, b1f, b2f);
}
__global__ __launch_bounds__(256) void k_gemm1(const void* A, const ushort* Bhi, const ushort* Blo,
                                               _Float16* featg, float* el, float* er, const int* flags) {
    __shared__ __align__(16) _Float16 sfe[4][16][72];
    int wave = threadIdx.x >> 6, lane = threadIdx.x & 63;
    int rt = blockIdx.x * 4 + wave;
    if (rt >= RTILES) return;
    gemm1_wave(A, Bhi, Blo, featg, el, er, flags[0], rt, blockIdx.y * 4, lane, sfe[wave]);
}
__global__ __launch_bounds__(256) void k_gemm2(const ushort* a2hi, const ushort* a2lo,
                                               const ushort* Bhi, const ushort* Blo,
                                               _Float16* featg, float* el, float* er, const int* flags) {
    __shared__ __align__(16) _Float16 sfe[4][16][72];
    int wave = threadIdx.x >> 6, lane = threadIdx.x & 63;
    int rt = blockIdx.x * 4 + wave;
    if (rt >= RTILES) return;
    gemm2_wave(a2hi, a2lo, Bhi, Blo, featg, el, er, flags[0], rt, blockIdx.y * 4, lane, sfe[wave]);
}
__global__ __launch_bounds__(256) void k_agg(const int* rowptr, const int* esrc, const half2v* featg,
                                             const float* el, const float* er, const float* bias,
                                             void* out, unsigned* olo, int mode, const int* flags) {
    int wave = threadIdx.x >> 6, lane = threadIdx.x & 63;
    int v = blockIdx.x * 4 + wave;
    if (v >= N_NODES) return;
    agg_node(rowptr, esrc, featg, el, er, bias, out, olo, mode, flags[0], v, lane);
}

extern "C" void kernel_launch(void* const* d_in, const int* in_sizes, int n_in,
                              void* d_out, int out_size, void* d_ws, size_t ws_size,
                              hipStream_t stream) {
    const void* node_feat = d_in[0];
    const int4* src4 = (const int4*)d_in[1];
    const int4* dst4 = (const int4*)d_in[2];
    const void* W1 = d_in[3];
    const void* al1 = d_in[4];
    const void* ar1 = d_in[5];
    const void* b1 = d_in[6];
    const void* W2 = d_in[7];
    const void* al2 = d_in[8];
    const void* ar2 = d_in[9];
    const void* b2 = d_in[10];
    void* dout = d_out;
    char* ws = (char*)d_ws;

    // size cooperative grid from real occupancy (same result every call)
    int nb = 0;
    hipError_t qe = hipOccupancyMaxActiveBlocksPerMultiprocessor(&nb, k_fused, 256, 0);
    if (qe != hipSuccess || nb < 1) nb = 1;
    int G = nb * 256;            // nb blocks/CU x 256 CUs
    if (G > 1536) G = 1536;
    if (G < 256) G = 256;

    void* kargs[13] = {(void*)&node_feat, (void*)&src4, (void*)&dst4,
                       (void*)&W1, (void*)&al1, (void*)&ar1, (void*)&b1,
                       (void*)&W2, (void*)&al2, (void*)&ar2, (void*)&b2,
                       (void*)&dout, (void*)&ws};
    hipError_t e = hipLaunchCooperativeKernel((const void*)k_fused, dim3(G), dim3(256), kargs, 0, stream);

    if (e != hipSuccess) {
        // -------- fallback: round-8 multi-kernel pipeline --------
        int* rowptr = (int*)(ws + O_ROWPTR);
        int* deg    = (int*)(ws + O_DEG);
        int* bsum   = (int*)(ws + O_BSUM);
        int* tmpsc  = (int*)(ws + O_TMPSCAN);
        int* flags  = (int*)(ws + O_FLAGS);
        int4* pos4  = (int4*)(ws + O_POS);
        int* esrc   = (int*)(ws + O_ESRC);
        ushort* w1hi = (ushort*)(ws + O_W1HI);
        ushort* w1lo = (ushort*)(ws + O_W1LO);
        ushort* w2hi = (ushort*)(ws + O_W2HI);
        ushort* w2lo = (ushort*)(ws + O_W2LO);
        float* b1f  = (float*)(ws + O_B1F);
        float* b2f  = (float*)(ws + O_B2F);
        _Float16* featg = (_Float16*)(ws + O_FEATG);
        float* el   = (float*)(ws + O_EL);
        float* er   = (float*)(ws + O_ER);
        ushort* a2hi = (ushort*)(ws + O_A2HI);
        ushort* a2lo = (ushort*)(ws + O_A2LO);

        const int EB4 = (N_EDGES / 4 + 255) / 256;
        const dim3 GG((RTILES + 3) / 4, 2);

        k_detect<<<1, 256, 0, stream>>>((const ushort*)W1, flags);
        hipMemsetAsync(ws + O_DEG, 0, N_NODES * 4, stream);
        k_count<<<EB4, 256, 0, stream>>>(dst4, deg, pos4);
        k_scan1<<<SCAN_BLKS, 256, 0, stream>>>(deg, tmpsc, bsum);
        k_scan23<<<SCAN_BLKS, 256, 0, stream>>>(tmpsc, bsum, rowptr);
        k_place<<<EB4, 256, 0, stream>>>(src4, dst4, rowptr, pos4, esrc);
        k_prep<<<217, 256, 0, stream>>>(W1, al1, ar1, b1, W2, al2, ar2, b2,
                                        w1hi, w1lo, w2hi, w2lo, b1f, b2f, flags);
        k_gemm1<<<GG, 256, 0, stream>>>(node_feat, w1hi, w1lo, featg, el, er, flags);
        k_agg<<<(N_NODES + 3) / 4, 256, 0, stream>>>(rowptr, esrc, (const half2v*)featg, el, er, b1f,
                                                     (void*)a2hi, (unsigned*)a2lo, 0, flags);
        k_gemm2<<<GG, 256, 0, stream>>>(a2hi, a2lo, w2hi, w2lo, featg, el, er, flags);
        k_agg<<<(N_NODES + 3) / 4, 256, 0, stream>>>(rowptr, esrc, (const half2v*)featg, el, er, b2f,
                                                     dout, nullptr, 1, flags);
    }
}

// Round 10
// 614.610 us; speedup vs baseline: 1.9147x; 1.9147x over previous
//
#include <hip/hip_runtime.h>
#include <hip/hip_bf16.h>

#define N_NODES 50000
#define N_EDGES 1600000
#define HEADS 8
#define HDIM 16
#define D1 128   // HEADS*HDIM
#define NEG_SLOPE 0.2f
#define SCAN_BLKS 196  // ceil(50000/256)
#define RTILES 3125    // 50000/16

typedef short short8 __attribute__((ext_vector_type(8)));
typedef float f32x4 __attribute__((ext_vector_type(4)));
typedef _Float16 half2v __attribute__((ext_vector_type(2)));

// ---- dtype helpers (isf32: 1 = buffers are fp32, 0 = bf16) ----
__device__ __forceinline__ float bf2f(ushort u) {
    union { unsigned u; float f; } x; x.u = ((unsigned)u) << 16; return x.f;
}
__device__ __forceinline__ ushort f2bf(float f) {
    union { float f; unsigned u; } x; x.f = f;
    unsigned r = x.u + 0x7FFF + ((x.u >> 16) & 1);   // RNE
    return (ushort)(r >> 16);
}
__device__ __forceinline__ float ldf(const void* p, size_t i, int isf32) {
    return isf32 ? ((const float*)p)[i] : bf2f(((const ushort*)p)[i]);
}
__device__ __forceinline__ void splitbf(float f, ushort& hi, ushort& lo) {
    unsigned u = __float_as_uint(f);
    unsigned uh = u & 0xFFFF0000u;
    hi = (ushort)(uh >> 16);
    lo = f2bf(f - __uint_as_float(uh));
}

// ---------------- workspace layout (bytes) ----------------
#define O_ROWPTR   0
#define O_DEG      200064
#define O_BSUM     400128
#define O_TMPSCAN  408320
#define O_FLAGS    608384
#define O_POS      608640
#define O_ESRC     7008640
#define O_W1HI     13408640      // 144x256 bf16 = 73728*2
#define O_W1LO     13556096
#define O_W2F      13703552      // 128x160 fp32 = 81920
#define O_B1F      13851008
#define O_B2F      13851520
#define O_FEATG    13852032      // fp16 [N][128] layer-1 features
#define O_EL       26652032
#define O_ER       28252032
#define O_FEATG2   29852032      // fp16 [N][128] layer-2 features
#define O_EL2      42652032
#define O_ER2      44252032

// ================= device helpers =================

__device__ __forceinline__ void detect_body(const ushort* w1, int* flags, int* sm) {
    int t = threadIdx.x;
    int cnt = 0;
    for (int i = t; i < 32768; i += 256) {
        int e = (w1[i] >> 7) & 0xFF;
        if (e >= 0xC8) cnt++;
    }
    sm[t] = cnt; __syncthreads();
    for (int off = 128; off > 0; off >>= 1) {
        if (t < off) sm[t] += sm[t + off];
        __syncthreads();
    }
    if (t == 0) flags[0] = (sm[0] > 0) ? 1 : 0;
}

// ---- phase A: zero deg (blocks 0..195) + dtype detect (block 196) ----
__global__ __launch_bounds__(256) void k_zerodetect(const ushort* __restrict__ w1,
                                                    int* __restrict__ deg, int* __restrict__ flags) {
    __shared__ int sm[256];
    int b = blockIdx.x;
    if (b < SCAN_BLKS) {
        int i = b * 256 + threadIdx.x;
        if (i < N_NODES) deg[i] = 0;
    } else {
        detect_body(w1, flags, sm);
    }
}

// ---- weight prep pieces ----
// W1 -> w1hi/w1lo bf16 [144][256] transposed (cols 0..127 = W1 cols, 128..135 = W1@al1, 136..143 = W1@ar1)
__device__ __forceinline__ void wprep1_elem(const void* W, const void* al, const void* ar,
                                            ushort* whi, ushort* wlo, int isf32, int idx) {
    const int K = 256;
    int n = idx >> 8, k = idx & 255;
    float f;
    if (n < 128) {
        f = ldf(W, (size_t)k * 128 + n, isf32);
    } else if (n < 136) {
        int h = n - 128;
        f = 0.f;
#pragma unroll
        for (int d = 0; d < HDIM; ++d)
            f = fmaf(ldf(W, (size_t)k * 128 + h * 16 + d, isf32), ldf(al, h * 16 + d, isf32), f);
    } else {
        int h = n - 136;
        f = 0.f;
#pragma unroll
        for (int d = 0; d < HDIM; ++d)
            f = fmaf(ldf(W, (size_t)k * 128 + h * 16 + d, isf32), ldf(ar, h * 16 + d, isf32), f);
    }
    ushort hi = f2bf(f);
    wlo[n * K + k] = f2bf(f - bf2f(hi));
    whi[n * K + k] = hi;
}

// W2 -> w2f fp32 [128][160]: cols 0..127 = W2 row, 128..135 = (W2@al2)[k][h], 136..143 = (W2@ar2)
__device__ __forceinline__ void wprep2_elem(const void* W, const void* al, const void* ar,
                                            float* w2f, int isf32, int idx) {
    if (idx >= 128 * 144) return;
    int k = idx & 127, n = idx >> 7;
    float f;
    if (n < 128) {
        f = ldf(W, (size_t)k * 128 + n, isf32);
    } else if (n < 136) {
        int h = n - 128;
        f = 0.f;
#pragma unroll
        for (int d = 0; d < HDIM; ++d)
            f = fmaf(ldf(W, (size_t)k * 128 + h * 16 + d, isf32), ldf(al, h * 16 + d, isf32), f);
    } else {
        int h = n - 136;
        f = 0.f;
#pragma unroll
        for (int d = 0; d < HDIM; ++d)
            f = fmaf(ldf(W, (size_t)k * 128 + h * 16 + d, isf32), ldf(ar, h * 16 + d, isf32), f);
    }
    w2f[k * 160 + n] = f;
}

// ---- phase B: edge count (blocks 0..1562) + weight prep (blocks 1563..1779) ----
__global__ __launch_bounds__(256) void k_countprep(const int4* __restrict__ dst4, int* __restrict__ deg,
                                                   int4* __restrict__ pos4,
                                                   const void* __restrict__ W1, const void* __restrict__ al1,
                                                   const void* __restrict__ ar1, const void* __restrict__ b1,
                                                   const void* __restrict__ W2, const void* __restrict__ al2,
                                                   const void* __restrict__ ar2, const void* __restrict__ b2,
                                                   ushort* __restrict__ w1hi, ushort* __restrict__ w1lo,
                                                   float* __restrict__ w2f,
                                                   float* __restrict__ b1f, float* __restrict__ b2f,
                                                   const int* __restrict__ flags) {
    int b = blockIdx.x, t = threadIdx.x;
    if (b < 1563) {
        int i = b * 256 + t;
        if (i < N_EDGES / 4) {
            int4 d = dst4[i];
            int4 p;
            p.x = atomicAdd(&deg[d.x], 1);
            p.y = atomicAdd(&deg[d.y], 1);
            p.z = atomicAdd(&deg[d.z], 1);
            p.w = atomicAdd(&deg[d.w], 1);
            pos4[i] = p;
        }
    } else {
        int isf32 = flags[0];
        int u = b - 1563;
        if (u < 144) {
            wprep1_elem(W1, al1, ar1, w1hi, w1lo, isf32, u * 256 + t);
        } else if (u < 216) {
            wprep2_elem(W2, al2, ar2, w2f, isf32, (u - 144) * 256 + t);
        } else {
            if (t < 128) b1f[t] = ldf(b1, t, isf32);
            else b2f[t - 128] = ldf(b2, t - 128, isf32);
        }
    }
}

__global__ __launch_bounds__(256) void k_scan1(const int* __restrict__ deg, int* __restrict__ tmp,
                                               int* __restrict__ bsum) {
    __shared__ int sm[256];
    int t = threadIdx.x;
    int i = blockIdx.x * 256 + t;
    int x = (i < N_NODES) ? deg[i] : 0;
    sm[t] = x; __syncthreads();
    for (int off = 1; off < 256; off <<= 1) {
        int v = (t >= off) ? sm[t - off] : 0;
        __syncthreads();
        sm[t] += v;
        __syncthreads();
    }
    if (i < N_NODES) tmp[i] = sm[t];
    if (t == 255) bsum[blockIdx.x] = sm[255];
}

__global__ __launch_bounds__(256) void k_scan23(const int* __restrict__ tmp, const int* __restrict__ bsum,
                                                int* __restrict__ rowptr) {
    __shared__ int sm[256];
    int t = threadIdx.x;
    int x = (t < SCAN_BLKS) ? bsum[t] : 0;
    sm[t] = x; __syncthreads();
    for (int off = 1; off < 256; off <<= 1) {
        int v = (t >= off) ? sm[t - off] : 0;
        __syncthreads();
        sm[t] += v;
        __syncthreads();
    }
    int boff = sm[blockIdx.x] - ((blockIdx.x < SCAN_BLKS) ? bsum[blockIdx.x] : 0);
    int i = blockIdx.x * 256 + t;
    if (i < N_NODES) rowptr[i + 1] = tmp[i] + boff;
    if (i == 0) rowptr[0] = 0;
}

// coalesced featg tile store via per-wave LDS region
__device__ __forceinline__ void store_tile(_Float16 (*sfe)[72], _Float16* featg,
                                           const f32x4* acc, int lane, int quad, int l16,
                                           int rowb0, int cbase) {
#pragma unroll
    for (int ci = 0; ci < 4; ++ci)
#pragma unroll
        for (int r = 0; r < 4; ++r)
            sfe[quad * 4 + r][ci * 16 + l16] = (_Float16)acc[ci][r];
    int rr = lane >> 3, ch = lane & 7;
#pragma unroll
    for (int s = 0; s < 2; ++s) {
        int row = s * 8 + rr;
        short8 v = *(const short8*)&sfe[row][ch * 8];
        *(short8*)(featg + (size_t)(rowb0 + row) * D1 + cbase * 16 + ch * 8) = v;
    }
}

__device__ __forceinline__ void gemm1_wave(const void* A, const ushort* Bhi, const ushort* Blo,
                                           _Float16* featg, float* el, float* er,
                                           int isf32, int rt, int cbase, int lane,
                                           _Float16 (*sfe)[72]) {
    int quad = lane >> 4, l16 = lane & 15;
    const int K = 256;
    size_t a_off = (size_t)(rt * 16 + l16) * K + quad * 8;
    int rowb0 = rt * 16;

    short8 ahi[8], alo[8];
    if (isf32) {
        const float* ap = (const float*)A + a_off;
#pragma unroll
        for (int i = 0; i < 8; ++i) {
            f32x4 u0 = *(const f32x4*)(ap + 32 * i);
            f32x4 u1 = *(const f32x4*)(ap + 32 * i + 4);
            float a8[8] = {u0[0], u0[1], u0[2], u0[3], u1[0], u1[1], u1[2], u1[3]};
#pragma unroll
            for (int j = 0; j < 8; ++j) {
                ushort h, l;
                splitbf(a8[j], h, l);
                ahi[i][j] = (short)h; alo[i][j] = (short)l;
            }
        }
    } else {
        const ushort* ap = (const ushort*)A + a_off;
#pragma unroll
        for (int i = 0; i < 8; ++i) ahi[i] = *(const short8*)(ap + 32 * i);
    }

    f32x4 acc[4];
#pragma unroll
    for (int ci = 0; ci < 4; ++ci) acc[ci] = (f32x4){0.f, 0.f, 0.f, 0.f};
#pragma unroll
    for (int ci = 0; ci < 4; ++ci) {
        int c = cbase + ci;
        const ushort* bh = Bhi + (size_t)(c * 16 + l16) * K + quad * 8;
        if (isf32) {
            const ushort* bl = Blo + (size_t)(c * 16 + l16) * K + quad * 8;
#pragma unroll
            for (int k = 0; k < 8; ++k) {
                short8 bh8 = *(const short8*)(bh + 32 * k);
                short8 bl8 = *(const short8*)(bl + 32 * k);
                acc[ci] = __builtin_amdgcn_mfma_f32_16x16x32_bf16(ahi[k], bh8, acc[ci], 0, 0, 0);
                acc[ci] = __builtin_amdgcn_mfma_f32_16x16x32_bf16(ahi[k], bl8, acc[ci], 0, 0, 0);
                acc[ci] = __builtin_amdgcn_mfma_f32_16x16x32_bf16(alo[k], bh8, acc[ci], 0, 0, 0);
            }
        } else {
#pragma unroll
            for (int k = 0; k < 8; ++k) {
                short8 bh8 = *(const short8*)(bh + 32 * k);
                acc[ci] = __builtin_amdgcn_mfma_f32_16x16x32_bf16(ahi[k], bh8, acc[ci], 0, 0, 0);
            }
        }
    }
    store_tile(sfe, featg, acc, lane, quad, l16, rowb0, cbase);

    if (cbase == 4) {   // el/er fold tile (c=8)
        const ushort* bh = Bhi + (size_t)(8 * 16 + l16) * K + quad * 8;
        const ushort* bl = Blo + (size_t)(8 * 16 + l16) * K + quad * 8;
        f32x4 a = {0.f, 0.f, 0.f, 0.f};
#pragma unroll
        for (int k = 0; k < 8; ++k) {
            short8 bh8 = *(const short8*)(bh + 32 * k);
            short8 bl8 = *(const short8*)(bl + 32 * k);
            a = __builtin_amdgcn_mfma_f32_16x16x32_bf16(ahi[k], bh8, a, 0, 0, 0);
            a = __builtin_amdgcn_mfma_f32_16x16x32_bf16(ahi[k], bl8, a, 0, 0, 0);
            if (isf32) a = __builtin_amdgcn_mfma_f32_16x16x32_bf16(alo[k], bh8, a, 0, 0, 0);
        }
#pragma unroll
        for (int r = 0; r < 4; ++r) {
            int row = rowb0 + quad * 4 + r;
            if (l16 < 8) el[row * 8 + l16] = a[r];
            else         er[row * 8 + (l16 - 8)] = a[r];
        }
    }
}

// ---- phase C: place (blocks 0..1562) + gemm1 (blocks 1563..3126) ----
__global__ __launch_bounds__(256) void k_placegemm1(const int4* __restrict__ src4, const int4* __restrict__ dst4,
                                                    const int* __restrict__ rowptr, const int4* __restrict__ pos4,
                                                    int* __restrict__ esrc,
                                                    const void* __restrict__ A,
                                                    const ushort* __restrict__ w1hi, const ushort* __restrict__ w1lo,
                                                    _Float16* __restrict__ featg,
                                                    float* __restrict__ el, float* __restrict__ er,
                                                    const int* __restrict__ flags) {
    __shared__ __align__(16) _Float16 sfe[4][16][72];
    int b = blockIdx.x, t = threadIdx.x;
    if (b < 1563) {
        int i = b * 256 + t;
        if (i < N_EDGES / 4) {
            int4 s = src4[i], d = dst4[i], p = pos4[i];
            esrc[rowptr[d.x] + p.x] = s.x;
            esrc[rowptr[d.y] + p.y] = s.y;
            esrc[rowptr[d.z] + p.z] = s.z;
            esrc[rowptr[d.w] + p.w] = s.w;
        }
    } else {
        int bt = b - 1563;               // 0..1563
        int wave = t >> 6, lane = t & 63;
        int rt = (bt >> 1) * 4 + wave;
        int cbase = (bt & 1) * 4;
        if (rt < RTILES)
            gemm1_wave(A, w1hi, w1lo, featg, el, er, flags[0], rt, cbase, lane, sfe[wave]);
    }
}

// ---- shared gather core (batch-8 edges, one wave per node) ----
__device__ __forceinline__ void gather_core(const int* rowptr, const int* esrc, const half2v* featg,
                                            const float* el, const float* er, int v, int lane,
                                            float& acc0, float& acc1, float& den, int& deg) {
    int h8 = lane & 7;
    int esel = lane >> 3;
    float erv = er[v * 8 + h8];
    int beg = rowptr[v], end = rowptr[v + 1];
    deg = end - beg;
    acc0 = 0.f; acc1 = 0.f; den = 0.f;
    int jend = beg + (deg & ~7);
    for (int j = beg; j < jend; j += 8) {
        int sv = esrc[j + h8];
        int se = __shfl(sv, esel);
        float x = el[se * 8 + h8] + erv;
        x = x > 0.f ? x : NEG_SLOPE * x;
        float w = __expf(x);
        int s_[8];
#pragma unroll
        for (int e = 0; e < 8; ++e) s_[e] = __shfl(sv, e);
        half2v hh_[8];
#pragma unroll
        for (int e = 0; e < 8; ++e) hh_[e] = featg[(size_t)s_[e] * 64 + lane];
        float we_[8];
#pragma unroll
        for (int e = 0; e < 8; ++e) we_[e] = __shfl(w, e * 8 + esel);
#pragma unroll
        for (int e = 0; e < 8; ++e) {
            den += we_[e];
            acc0 = fmaf(we_[e], (float)hh_[e][0], acc0);
            acc1 = fmaf(we_[e], (float)hh_[e][1], acc1);
        }
    }
    int rem = deg & 7;
    if (rem) {
        int idx = jend + h8;
        if (idx >= end) idx = end - 1;
        int sv = esrc[idx];
        int se = __shfl(sv, esel);
        float x = el[se * 8 + h8] + erv;
        x = x > 0.f ? x : NEG_SLOPE * x;
        float w = __expf(x);
        for (int e = 0; e < rem; ++e) {
            float we = __shfl(w, e * 8 + esel);
            int s = __shfl(sv, e);
            half2v hh = featg[(size_t)s * 64 + lane];
            den += we;
            acc0 = fmaf(we, (float)hh[0], acc0);
            acc1 = fmaf(we, (float)hh[1], acc1);
        }
    }
}

// ---- phase D: agg layer 1 + fused dense layer-2 transform ----
// h (fp32, 2/lane) -> y = h@W2ext (fp32 VALU, W2 L2-resident) -> featg2 fp16, el2/er2 fp32
__global__ __launch_bounds__(256) void k_agg1d(const int* __restrict__ rowptr, const int* __restrict__ esrc,
                                               const half2v* __restrict__ featg,
                                               const float* __restrict__ el, const float* __restrict__ er,
                                               const float* __restrict__ b1f,
                                               const float* __restrict__ w2f,
                                               half2v* __restrict__ featg2,
                                               float* __restrict__ el2, float* __restrict__ er2) {
    int wave = threadIdx.x >> 6, lane = threadIdx.x & 63;
    int v = blockIdx.x * 4 + wave;
    if (v >= N_NODES) return;
    float acc0, acc1, den; int deg;
    gather_core(rowptr, esrc, featg, el, er, v, lane, acc0, acc1, den, deg);
    float inv = (deg > 0) ? 1.0f / den : 0.f;
    float2 bb = ((const float2*)b1f)[lane];
    float r0 = fmaf(acc0, inv, bb.x);
    float r1 = fmaf(acc1, inv, bb.y);
    r0 = r0 > 0.f ? r0 : (__expf(r0) - 1.f);   // ELU -> h[2*lane], h[2*lane+1]
    r1 = r1 > 0.f ? r1 : (__expf(r1) - 1.f);

    // dense: y_j = sum_k h_k * w2f[k][j]; lane owns j = 2*lane, 2*lane+1, + fold col 128+(lane&15)
    float y0 = 0.f, y1 = 0.f, z = 0.f;
    int fcol = 128 + (lane & 15);
#pragma unroll 8
    for (int kk = 0; kk < 64; ++kk) {
        float h0 = __shfl(r0, kk);           // h[2*kk]
        float h1 = __shfl(r1, kk);           // h[2*kk+1]
        const float* row0 = w2f + (2 * kk) * 160;
        const float* row1 = row0 + 160;
        float2 w0 = *(const float2*)(row0 + 2 * lane);
        float2 w1 = *(const float2*)(row1 + 2 * lane);
        float f0 = row0[fcol];
        float f1 = row1[fcol];
        y0 = fmaf(h0, w0.x, y0); y1 = fmaf(h0, w0.y, y1);
        y0 = fmaf(h1, w1.x, y0); y1 = fmaf(h1, w1.y, y1);
        z  = fmaf(h0, f0, z);    z  = fmaf(h1, f1, z);
    }
    half2v st; st[0] = (_Float16)y0; st[1] = (_Float16)y1;
    featg2[(size_t)v * 64 + lane] = st;
    if (lane < 8) el2[v * 8 + lane] = z;
    else if (lane < 16) er2[v * 8 + (lane - 8)] = z;
}

// ---- phase E: agg layer 2 -> head-mean -> d_out ----
__global__ __launch_bounds__(256) void k_agg2(const int* __restrict__ rowptr, const int* __restrict__ esrc,
                                              const half2v* __restrict__ featg2,
                                              const float* __restrict__ el2, const float* __restrict__ er2,
                                              const float* __restrict__ b2f,
                                              void* __restrict__ out, const int* __restrict__ flags) {
    int wave = threadIdx.x >> 6, lane = threadIdx.x & 63;
    int v = blockIdx.x * 4 + wave;
    if (v >= N_NODES) return;
    float acc0, acc1, den; int deg;
    gather_core(rowptr, esrc, featg2, el2, er2, v, lane, acc0, acc1, den, deg);
    float inv = (deg > 0) ? 1.0f / den : 0.f;
    float2 bb = ((const float2*)b2f)[lane];
    float r0 = fmaf(acc0, inv, bb.x);
    float r1 = fmaf(acc1, inv, bb.y);
    for (int m = 8; m < 64; m <<= 1) {
        r0 += __shfl_xor(r0, m);
        r1 += __shfl_xor(r1, m);
    }
    if (lane < 8) {
        float v0 = r0 * 0.125f, v1 = r1 * 0.125f;
        if (flags[0]) {
            float2 st = {v0, v1};
            ((float2*)out)[(size_t)v * 8 + lane] = st;
        } else {
            unsigned pk = (unsigned)f2bf(v0) | ((unsigned)f2bf(v1) << 16);
            ((unsigned*)out)[(size_t)v * 8 + lane] = pk;
        }
    }
}

extern "C" void kernel_launch(void* const* d_in, const int* in_sizes, int n_in,
                              void* d_out, int out_size, void* d_ws, size_t ws_size,
                              hipStream_t stream) {
    const void* node_feat = d_in[0];
    const int4* src4 = (const int4*)d_in[1];
    const int4* dst4 = (const int4*)d_in[2];
    const void* W1 = d_in[3];
    const void* al1 = d_in[4];
    const void* ar1 = d_in[5];
    const void* b1 = d_in[6];
    const void* W2 = d_in[7];
    const void* al2 = d_in[8];
    const void* ar2 = d_in[9];
    const void* b2 = d_in[10];
    char* ws = (char*)d_ws;

    int* rowptr = (int*)(ws + O_ROWPTR);
    int* deg    = (int*)(ws + O_DEG);
    int* bsum   = (int*)(ws + O_BSUM);
    int* tmpsc  = (int*)(ws + O_TMPSCAN);
    int* flags  = (int*)(ws + O_FLAGS);
    int4* pos4  = (int4*)(ws + O_POS);
    int* esrc   = (int*)(ws + O_ESRC);
    ushort* w1hi = (ushort*)(ws + O_W1HI);
    ushort* w1lo = (ushort*)(ws + O_W1LO);
    float* w2f  = (float*)(ws + O_W2F);
    float* b1f  = (float*)(ws + O_B1F);
    float* b2f  = (float*)(ws + O_B2F);
    _Float16* featg = (_Float16*)(ws + O_FEATG);
    float* el   = (float*)(ws + O_EL);
    float* er   = (float*)(ws + O_ER);
    half2v* featg2 = (half2v*)(ws + O_FEATG2);
    float* el2  = (float*)(ws + O_EL2);
    float* er2  = (float*)(ws + O_ER2);

    // A: zero deg + dtype detect
    k_zerodetect<<<SCAN_BLKS + 1, 256, 0, stream>>>((const ushort*)W1, deg, flags);
    // B: edge count (atomics) || weight prep (independent)
    k_countprep<<<1563 + 217, 256, 0, stream>>>(dst4, deg, pos4, W1, al1, ar1, b1,
                                                W2, al2, ar2, b2, w1hi, w1lo, w2f, b1f, b2f, flags);
    // scan
    k_scan1<<<SCAN_BLKS, 256, 0, stream>>>(deg, tmpsc, bsum);
    k_scan23<<<SCAN_BLKS, 256, 0, stream>>>(tmpsc, bsum, rowptr);
    // C: CSR place || gemm1 (independent)
    k_placegemm1<<<1563 + 1564, 256, 0, stream>>>(src4, dst4, rowptr, pos4, esrc,
                                                  node_feat, w1hi, w1lo, featg, el, er, flags);
    // D: agg layer 1 + fused layer-2 dense
    k_agg1d<<<(N_NODES + 3) / 4, 256, 0, stream>>>(rowptr, esrc, (const half2v*)featg, el, er,
                                                   b1f, w2f, featg2, el2, er2);
    // E: agg layer 2 -> output
    k_agg2<<<(N_NODES + 3) / 4, 256, 0, stream>>>(rowptr, esrc, featg2, el2, er2, b2f, d_out, flags);
}

// Round 11
// 455.046 us; speedup vs baseline: 2.5861x; 1.3507x over previous
//
#include <hip/hip_runtime.h>
#include <hip/hip_bf16.h>

#define N_NODES 50000
#define N_EDGES 1600000
#define HEADS 8
#define HDIM 16
#define D1 128   // HEADS*HDIM
#define NEG_SLOPE 0.2f
#define SCAN_BLKS 196  // ceil(50000/256)
#define RTILES 3125    // 50000/16

typedef short short8 __attribute__((ext_vector_type(8)));
typedef float f32x4 __attribute__((ext_vector_type(4)));
typedef _Float16 half2v __attribute__((ext_vector_type(2)));

// ---- dtype helpers (isf32: 1 = buffers are fp32, 0 = bf16) ----
__device__ __forceinline__ float bf2f(ushort u) {
    union { unsigned u; float f; } x; x.u = ((unsigned)u) << 16; return x.f;
}
__device__ __forceinline__ ushort f2bf(float f) {
    union { float f; unsigned u; } x; x.f = f;
    unsigned r = x.u + 0x7FFF + ((x.u >> 16) & 1);   // RNE
    return (ushort)(r >> 16);
}
__device__ __forceinline__ float ldf(const void* p, size_t i, int isf32) {
    return isf32 ? ((const float*)p)[i] : bf2f(((const ushort*)p)[i]);
}
__device__ __forceinline__ void splitbf(float f, ushort& hi, ushort& lo) {
    unsigned u = __float_as_uint(f);
    unsigned uh = u & 0xFFFF0000u;
    hi = (ushort)(uh >> 16);
    lo = f2bf(f - __uint_as_float(uh));
}

// ---------------- workspace layout (bytes) ----------------
#define O_ROWPTR   0
#define O_DEG      200064
#define O_BSUM     400128
#define O_TMPSCAN  408320
#define O_FLAGS    608384
#define O_POS      608640
#define O_ESRC     7008640
#define O_W1HI     13408640      // 144x256 bf16
#define O_W1LO     13556096
#define O_W2HI     13703552      // 144x128 bf16
#define O_W2LO     13777280
#define O_B1F      13851008
#define O_B2F      13851520
#define O_FEATG    13852032      // fp16 [N][128], reused by both layers
#define O_EL       26652032
#define O_ER       28252032
#define O_A2HI     29852032      // bf16 hi of layer-1 h
#define O_A2LO     42652032      // bf16 lo of layer-1 h

// ================= device helpers =================

__device__ __forceinline__ void detect_body(const ushort* w1, int* flags, int* sm) {
    int t = threadIdx.x;
    int cnt = 0;
    for (int i = t; i < 32768; i += 256) {
        int e = (w1[i] >> 7) & 0xFF;
        if (e >= 0xC8) cnt++;
    }
    sm[t] = cnt; __syncthreads();
    for (int off = 128; off > 0; off >>= 1) {
        if (t < off) sm[t] += sm[t + off];
        __syncthreads();
    }
    if (t == 0) flags[0] = (sm[0] > 0) ? 1 : 0;
}

// ---- phase A: zero deg (blocks 0..195) + dtype detect (block 196) ----
__global__ __launch_bounds__(256) void k_zerodetect(const ushort* __restrict__ w1,
                                                    int* __restrict__ deg, int* __restrict__ flags) {
    __shared__ int sm[256];
    int b = blockIdx.x;
    if (b < SCAN_BLKS) {
        int i = b * 256 + threadIdx.x;
        if (i < N_NODES) deg[i] = 0;
    } else {
        detect_body(w1, flags, sm);
    }
}

// W -> whi/wlo bf16 [144][K] transposed (rows 0..127 = W cols, 128..135 = W@al, 136..143 = W@ar)
__device__ __forceinline__ void wprep_elem(const void* W, const void* al, const void* ar,
                                           int K, int kshift, ushort* whi, ushort* wlo,
                                           int isf32, int idx) {
    if (idx >= 144 * K) return;
    int n = idx >> kshift, k = idx & (K - 1);
    float f;
    if (n < 128) {
        f = ldf(W, (size_t)k * 128 + n, isf32);
    } else if (n < 136) {
        int h = n - 128;
        f = 0.f;
#pragma unroll
        for (int d = 0; d < HDIM; ++d)
            f = fmaf(ldf(W, (size_t)k * 128 + h * 16 + d, isf32), ldf(al, h * 16 + d, isf32), f);
    } else {
        int h = n - 136;
        f = 0.f;
#pragma unroll
        for (int d = 0; d < HDIM; ++d)
            f = fmaf(ldf(W, (size_t)k * 128 + h * 16 + d, isf32), ldf(ar, h * 16 + d, isf32), f);
    }
    ushort hi = f2bf(f);
    wlo[n * K + k] = f2bf(f - bf2f(hi));
    whi[n * K + k] = hi;
}

// ---- phase B: edge count (blocks 0..1562) + weight prep (blocks 1563..1779) ----
__global__ __launch_bounds__(256) void k_countprep(const int4* __restrict__ dst4, int* __restrict__ deg,
                                                   int4* __restrict__ pos4,
                                                   const void* __restrict__ W1, const void* __restrict__ al1,
                                                   const void* __restrict__ ar1, const void* __restrict__ b1,
                                                   const void* __restrict__ W2, const void* __restrict__ al2,
                                                   const void* __restrict__ ar2, const void* __restrict__ b2,
                                                   ushort* __restrict__ w1hi, ushort* __restrict__ w1lo,
                                                   ushort* __restrict__ w2hi, ushort* __restrict__ w2lo,
                                                   float* __restrict__ b1f, float* __restrict__ b2f,
                                                   const int* __restrict__ flags) {
    int b = blockIdx.x, t = threadIdx.x;
    if (b < 1563) {
        int i = b * 256 + t;
        if (i < N_EDGES / 4) {
            int4 d = dst4[i];
            int4 p;
            p.x = atomicAdd(&deg[d.x], 1);
            p.y = atomicAdd(&deg[d.y], 1);
            p.z = atomicAdd(&deg[d.z], 1);
            p.w = atomicAdd(&deg[d.w], 1);
            pos4[i] = p;
        }
    } else {
        int isf32 = flags[0];
        int u = b - 1563;
        if (u < 144) {
            wprep_elem(W1, al1, ar1, 256, 8, w1hi, w1lo, isf32, u * 256 + t);
        } else if (u < 216) {
            wprep_elem(W2, al2, ar2, 128, 7, w2hi, w2lo, isf32, (u - 144) * 256 + t);
        } else {
            if (t < 128) b1f[t] = ldf(b1, t, isf32);
            else b2f[t - 128] = ldf(b2, t - 128, isf32);
        }
    }
}

__global__ __launch_bounds__(256) void k_scan1(const int* __restrict__ deg, int* __restrict__ tmp,
                                               int* __restrict__ bsum) {
    __shared__ int sm[256];
    int t = threadIdx.x;
    int i = blockIdx.x * 256 + t;
    int x = (i < N_NODES) ? deg[i] : 0;
    sm[t] = x; __syncthreads();
    for (int off = 1; off < 256; off <<= 1) {
        int v = (t >= off) ? sm[t - off] : 0;
        __syncthreads();
        sm[t] += v;
        __syncthreads();
    }
    if (i < N_NODES) tmp[i] = sm[t];
    if (t == 255) bsum[blockIdx.x] = sm[255];
}

__global__ __launch_bounds__(256) void k_scan23(const int* __restrict__ tmp, const int* __restrict__ bsum,
                                                int* __restrict__ rowptr) {
    __shared__ int sm[256];
    int t = threadIdx.x;
    int x = (t < SCAN_BLKS) ? bsum[t] : 0;
    sm[t] = x; __syncthreads();
    for (int off = 1; off < 256; off <<= 1) {
        int v = (t >= off) ? sm[t - off] : 0;
        __syncthreads();
        sm[t] += v;
        __syncthreads();
    }
    int boff = sm[blockIdx.x] - ((blockIdx.x < SCAN_BLKS) ? bsum[blockIdx.x] : 0);
    int i = blockIdx.x * 256 + t;
    if (i < N_NODES) rowptr[i + 1] = tmp[i] + boff;
    if (i == 0) rowptr[0] = 0;
}

// coalesced featg tile store via per-wave LDS region (rows 144 B, 16B-aligned)
__device__ __forceinline__ void store_tile(_Float16 (*sfe)[72], _Float16* featg,
                                           const f32x4* acc, int lane, int quad, int l16,
                                           int rowb0, int cbase) {
#pragma unroll
    for (int ci = 0; ci < 4; ++ci)
#pragma unroll
        for (int r = 0; r < 4; ++r)
            sfe[quad * 4 + r][ci * 16 + l16] = (_Float16)acc[ci][r];
    int rr = lane >> 3, ch = lane & 7;
#pragma unroll
    for (int s = 0; s < 2; ++s) {
        int row = s * 8 + rr;
        short8 v = *(const short8*)&sfe[row][ch * 8];
        *(short8*)(featg + (size_t)(rowb0 + row) * D1 + cbase * 16 + ch * 8) = v;
    }
}

// gemm1, 9 c-tiles per wave (A fetched ONCE into registers)
__device__ __forceinline__ void gemm1_wave9(const void* A, const ushort* Bhi, const ushort* Blo,
                                            _Float16* featg, float* el, float* er,
                                            int isf32, int rt, int lane, _Float16 (*sfe)[72]) {
    int quad = lane >> 4, l16 = lane & 15;
    const int K = 256;
    size_t a_off = (size_t)(rt * 16 + l16) * K + quad * 8;
    int rowb0 = rt * 16;

    short8 ahi[8], alo[8];
    if (isf32) {
        const float* ap = (const float*)A + a_off;
#pragma unroll
        for (int i = 0; i < 8; ++i) {
            f32x4 u0 = *(const f32x4*)(ap + 32 * i);
            f32x4 u1 = *(const f32x4*)(ap + 32 * i + 4);
            float a8[8] = {u0[0], u0[1], u0[2], u0[3], u1[0], u1[1], u1[2], u1[3]};
#pragma unroll
            for (int j = 0; j < 8; ++j) {
                ushort h, l;
                splitbf(a8[j], h, l);
                ahi[i][j] = (short)h; alo[i][j] = (short)l;
            }
        }
    } else {
        const ushort* ap = (const ushort*)A + a_off;
#pragma unroll
        for (int i = 0; i < 8; ++i) ahi[i] = *(const short8*)(ap + 32 * i);
    }

#pragma unroll
    for (int g = 0; g < 2; ++g) {
        f32x4 acc[4];
#pragma unroll
        for (int ci = 0; ci < 4; ++ci) acc[ci] = (f32x4){0.f, 0.f, 0.f, 0.f};
#pragma unroll
        for (int ci = 0; ci < 4; ++ci) {
            int c = g * 4 + ci;
            const ushort* bh = Bhi + (size_t)(c * 16 + l16) * K + quad * 8;
            if (isf32) {
                const ushort* bl = Blo + (size_t)(c * 16 + l16) * K + quad * 8;
#pragma unroll
                for (int k = 0; k < 8; ++k) {
                    short8 bh8 = *(const short8*)(bh + 32 * k);
                    short8 bl8 = *(const short8*)(bl + 32 * k);
                    acc[ci] = __builtin_amdgcn_mfma_f32_16x16x32_bf16(ahi[k], bh8, acc[ci], 0, 0, 0);
                    acc[ci] = __builtin_amdgcn_mfma_f32_16x16x32_bf16(ahi[k], bl8, acc[ci], 0, 0, 0);
                    acc[ci] = __builtin_amdgcn_mfma_f32_16x16x32_bf16(alo[k], bh8, acc[ci], 0, 0, 0);
                }
            } else {
#pragma unroll
                for (int k = 0; k < 8; ++k) {
                    short8 bh8 = *(const short8*)(bh + 32 * k);
                    acc[ci] = __builtin_amdgcn_mfma_f32_16x16x32_bf16(ahi[k], bh8, acc[ci], 0, 0, 0);
                }
            }
        }
        store_tile(sfe, featg, acc, lane, quad, l16, rowb0, g * 4);
    }

    // el/er fold tile (c=8)
    {
        const ushort* bh = Bhi + (size_t)(8 * 16 + l16) * K + quad * 8;
        const ushort* bl = Blo + (size_t)(8 * 16 + l16) * K + quad * 8;
        f32x4 a = {0.f, 0.f, 0.f, 0.f};
#pragma unroll
        for (int k = 0; k < 8; ++k) {
            short8 bh8 = *(const short8*)(bh + 32 * k);
            short8 bl8 = *(const short8*)(bl + 32 * k);
            a = __builtin_amdgcn_mfma_f32_16x16x32_bf16(ahi[k], bh8, a, 0, 0, 0);
            a = __builtin_amdgcn_mfma_f32_16x16x32_bf16(ahi[k], bl8, a, 0, 0, 0);
            if (isf32) a = __builtin_amdgcn_mfma_f32_16x16x32_bf16(alo[k], bh8, a, 0, 0, 0);
        }
#pragma unroll
        for (int r = 0; r < 4; ++r) {
            int row = rowb0 + quad * 4 + r;
            if (l16 < 8) el[row * 8 + l16] = a[r];
            else         er[row * 8 + (l16 - 8)] = a[r];
        }
    }
}

// ---- phase C: place (blocks 0..1562) + gemm1 (blocks 1563..2344) ----
__global__ __launch_bounds__(256) void k_placegemm1(const int4* __restrict__ src4, const int4* __restrict__ dst4,
                                                    const int* __restrict__ rowptr, const int4* __restrict__ pos4,
                                                    int* __restrict__ esrc,
                                                    const void* __restrict__ A,
                                                    const ushort* __restrict__ w1hi, const ushort* __restrict__ w1lo,
                                                    _Float16* __restrict__ featg,
                                                    float* __restrict__ el, float* __restrict__ er,
                                                    const int* __restrict__ flags) {
    __shared__ __align__(16) _Float16 sfe[4][16][72];
    int b = blockIdx.x, t = threadIdx.x;
    if (b < 1563) {
        int i = b * 256 + t;
        if (i < N_EDGES / 4) {
            int4 s = src4[i], d = dst4[i], p = pos4[i];
            esrc[rowptr[d.x] + p.x] = s.x;
            esrc[rowptr[d.y] + p.y] = s.y;
            esrc[rowptr[d.z] + p.z] = s.z;
            esrc[rowptr[d.w] + p.w] = s.w;
        }
    } else {
        int wave = t >> 6, lane = t & 63;
        int rt = (b - 1563) * 4 + wave;
        if (rt < RTILES)
            gemm1_wave9(A, w1hi, w1lo, featg, el, er, flags[0], rt, lane, sfe[wave]);
    }
}

// ---------------- GEMM layer 2: A pre-split (a2hi/a2lo bf16), K=128, grid (782,2) ----------------
__global__ __launch_bounds__(256) void k_gemm2(const ushort* __restrict__ a2hi, const ushort* __restrict__ a2lo,
                                               const ushort* __restrict__ Bhi, const ushort* __restrict__ Blo,
                                               _Float16* __restrict__ featg,
                                               float* __restrict__ el, float* __restrict__ er,
                                               const int* __restrict__ flags) {
    __shared__ __align__(16) _Float16 sfe[4][16][72];
    int isf32 = flags[0];
    int wave = threadIdx.x >> 6, lane = threadIdx.x & 63;
    int rt = blockIdx.x * 4 + wave;
    if (rt >= RTILES) return;
    int cbase = blockIdx.y * 4;
    int quad = lane >> 4, l16 = lane & 15;
    const int K = 128;
    size_t a_off = (size_t)(rt * 16 + l16) * K + quad * 8;
    int rowb0 = rt * 16;

    short8 ahi[4], alo[4];
#pragma unroll
    for (int i = 0; i < 4; ++i) ahi[i] = *(const short8*)(a2hi + a_off + 32 * i);
#pragma unroll
    for (int i = 0; i < 4; ++i) alo[i] = *(const short8*)(a2lo + a_off + 32 * i);

    f32x4 acc[4];
#pragma unroll
    for (int ci = 0; ci < 4; ++ci) acc[ci] = (f32x4){0.f, 0.f, 0.f, 0.f};
#pragma unroll
    for (int ci = 0; ci < 4; ++ci) {
        int c = cbase + ci;
        const ushort* bh = Bhi + (size_t)(c * 16 + l16) * K + quad * 8;
        const ushort* bl = Blo + (size_t)(c * 16 + l16) * K + quad * 8;
#pragma unroll
        for (int k = 0; k < 4; ++k) {
            short8 bh8 = *(const short8*)(bh + 32 * k);
            acc[ci] = __builtin_amdgcn_mfma_f32_16x16x32_bf16(ahi[k], bh8, acc[ci], 0, 0, 0);
            acc[ci] = __builtin_amdgcn_mfma_f32_16x16x32_bf16(alo[k], bh8, acc[ci], 0, 0, 0);
            if (isf32) {
                short8 bl8 = *(const short8*)(bl + 32 * k);
                acc[ci] = __builtin_amdgcn_mfma_f32_16x16x32_bf16(ahi[k], bl8, acc[ci], 0, 0, 0);
            }
        }
    }
    store_tile(sfe[wave], featg, acc, lane, quad, l16, rowb0, cbase);

    if (cbase == 4) {
        const ushort* bh = Bhi + (size_t)(8 * 16 + l16) * K + quad * 8;
        const ushort* bl = Blo + (size_t)(8 * 16 + l16) * K + quad * 8;
        f32x4 a = {0.f, 0.f, 0.f, 0.f};
#pragma unroll
        for (int k = 0; k < 4; ++k) {
            short8 bh8 = *(const short8*)(bh + 32 * k);
            short8 bl8 = *(const short8*)(bl + 32 * k);
            a = __builtin_amdgcn_mfma_f32_16x16x32_bf16(ahi[k], bh8, a, 0, 0, 0);
            a = __builtin_amdgcn_mfma_f32_16x16x32_bf16(ahi[k], bl8, a, 0, 0, 0);
            a = __builtin_amdgcn_mfma_f32_16x16x32_bf16(alo[k], bh8, a, 0, 0, 0);
        }
#pragma unroll
        for (int r = 0; r < 4; ++r) {
            int row = rowb0 + quad * 4 + r;
            if (l16 < 8) el[row * 8 + l16] = a[r];
            else         er[row * 8 + (l16 - 8)] = a[r];
        }
    }
}

// ---------------- aggregate: one wave per dst node, batch-8 edges ----------------
__global__ __launch_bounds__(256) void k_agg(const int* __restrict__ rowptr, const int* __restrict__ esrc,
                                             const half2v* __restrict__ featg,
                                             const float* __restrict__ el, const float* __restrict__ er,
                                             const float* __restrict__ bias,
                                             void* __restrict__ out, unsigned* __restrict__ olo,
                                             int mode, const int* __restrict__ flags) {
    int wv = threadIdx.x >> 6;
    int lane = threadIdx.x & 63;
    int v = blockIdx.x * 4 + wv;
    if (v >= N_NODES) return;
    int h8 = lane & 7;
    int esel = lane >> 3;
    float erv = er[v * 8 + h8];
    int beg = rowptr[v], end = rowptr[v + 1];
    int deg = end - beg;
    float acc0 = 0.f, acc1 = 0.f, den = 0.f;
    int jend = beg + (deg & ~7);
    for (int j = beg; j < jend; j += 8) {
        int sv = esrc[j + h8];
        int se = __shfl(sv, esel);
        float x = el[se * 8 + h8] + erv;
        x = x > 0.f ? x : NEG_SLOPE * x;
        float w = __expf(x);
        int s_[8];
#pragma unroll
        for (int e = 0; e < 8; ++e) s_[e] = __shfl(sv, e);
        half2v hh_[8];
#pragma unroll
        for (int e = 0; e < 8; ++e) hh_[e] = featg[(size_t)s_[e] * 64 + lane];
        float we_[8];
#pragma unroll
        for (int e = 0; e < 8; ++e) we_[e] = __shfl(w, e * 8 + esel);
#pragma unroll
        for (int e = 0; e < 8; ++e) {
            den += we_[e];
            acc0 = fmaf(we_[e], (float)hh_[e][0], acc0);
            acc1 = fmaf(we_[e], (float)hh_[e][1], acc1);
        }
    }
    int rem = deg & 7;
    if (rem) {
        int idx = jend + h8;
        if (idx >= end) idx = end - 1;
        int sv = esrc[idx];
        int se = __shfl(sv, esel);
        float x = el[se * 8 + h8] + erv;
        x = x > 0.f ? x : NEG_SLOPE * x;
        float w = __expf(x);
        for (int e = 0; e < rem; ++e) {
            float we = __shfl(w, e * 8 + esel);
            int s = __shfl(sv, e);
            half2v hh = featg[(size_t)s * 64 + lane];
            den += we;
            acc0 = fmaf(we, (float)hh[0], acc0);
            acc1 = fmaf(we, (float)hh[1], acc1);
        }
    }
    float inv = (deg > 0) ? 1.0f / den : 0.f;
    float2 bb = ((const float2*)bias)[lane];
    float r0 = fmaf(acc0, inv, bb.x);
    float r1 = fmaf(acc1, inv, bb.y);
    if (mode == 0) {
        r0 = r0 > 0.f ? r0 : (__expf(r0) - 1.f);   // ELU
        r1 = r1 > 0.f ? r1 : (__expf(r1) - 1.f);
        ushort h0, l0, h1, l1;
        splitbf(r0, h0, l0);
        splitbf(r1, h1, l1);
        ((unsigned*)out)[(size_t)v * 64 + lane] = (unsigned)h0 | ((unsigned)h1 << 16);
        olo[(size_t)v * 64 + lane] = (unsigned)l0 | ((unsigned)l1 << 16);
    } else {
        for (int m = 8; m < 64; m <<= 1) {
            r0 += __shfl_xor(r0, m);
            r1 += __shfl_xor(r1, m);
        }
        if (lane < 8) {
            float v0 = r0 * 0.125f, v1 = r1 * 0.125f;
            if (flags[0]) {
                float2 st = {v0, v1};
                ((float2*)out)[(size_t)v * 8 + lane] = st;
            } else {
                unsigned pk = (unsigned)f2bf(v0) | ((unsigned)f2bf(v1) << 16);
                ((unsigned*)out)[(size_t)v * 8 + lane] = pk;
            }
        }
    }
}

extern "C" void kernel_launch(void* const* d_in, const int* in_sizes, int n_in,
                              void* d_out, int out_size, void* d_ws, size_t ws_size,
                              hipStream_t stream) {
    const void* node_feat = d_in[0];
    const int4* src4 = (const int4*)d_in[1];
    const int4* dst4 = (const int4*)d_in[2];
    const void* W1 = d_in[3];
    const void* al1 = d_in[4];
    const void* ar1 = d_in[5];
    const void* b1 = d_in[6];
    const void* W2 = d_in[7];
    const void* al2 = d_in[8];
    const void* ar2 = d_in[9];
    const void* b2 = d_in[10];
    char* ws = (char*)d_ws;

    int* rowptr = (int*)(ws + O_ROWPTR);
    int* deg    = (int*)(ws + O_DEG);
    int* bsum   = (int*)(ws + O_BSUM);
    int* tmpsc  = (int*)(ws + O_TMPSCAN);
    int* flags  = (int*)(ws + O_FLAGS);
    int4* pos4  = (int4*)(ws + O_POS);
    int* esrc   = (int*)(ws + O_ESRC);
    ushort* w1hi = (ushort*)(ws + O_W1HI);
    ushort* w1lo = (ushort*)(ws + O_W1LO);
    ushort* w2hi = (ushort*)(ws + O_W2HI);
    ushort* w2lo = (ushort*)(ws + O_W2LO);
    float* b1f  = (float*)(ws + O_B1F);
    float* b2f  = (float*)(ws + O_B2F);
    _Float16* featg = (_Float16*)(ws + O_FEATG);
    float* el   = (float*)(ws + O_EL);
    float* er   = (float*)(ws + O_ER);
    ushort* a2hi = (ushort*)(ws + O_A2HI);
    ushort* a2lo = (ushort*)(ws + O_A2LO);

    // A: zero deg + dtype detect
    k_zerodetect<<<SCAN_BLKS + 1, 256, 0, stream>>>((const ushort*)W1, deg, flags);
    // B: edge count (atomics) || weight prep (independent)
    k_countprep<<<1563 + 217, 256, 0, stream>>>(dst4, deg, pos4, W1, al1, ar1, b1,
                                                W2, al2, ar2, b2, w1hi, w1lo, w2hi, w2lo,
                                                b1f, b2f, flags);
    // scans
    k_scan1<<<SCAN_BLKS, 256, 0, stream>>>(deg, tmpsc, bsum);
    k_scan23<<<SCAN_BLKS, 256, 0, stream>>>(tmpsc, bsum, rowptr);
    // C: CSR place || gemm1 (independent; gemm1 fetches A once)
    k_placegemm1<<<1563 + 782, 256, 0, stream>>>(src4, dst4, rowptr, pos4, esrc,
                                                 node_feat, w1hi, w1lo, featg, el, er, flags);
    // agg layer 1 -> split-bf16 h
    k_agg<<<(N_NODES + 3) / 4, 256, 0, stream>>>(rowptr, esrc, (const half2v*)featg, el, er, b1f,
                                                 (void*)a2hi, (unsigned*)a2lo, 0, flags);
    // gemm2 (MFMA)
    k_gemm2<<<dim3(782, 2), 256, 0, stream>>>(a2hi, a2lo, w2hi, w2lo, featg, el, er, flags);
    // agg layer 2 -> output
    k_agg<<<(N_NODES + 3) / 4, 256, 0, stream>>>(rowptr, esrc, (const half2v*)featg, el, er, b2f,
                                                 d_out, nullptr, 1, flags);
}

// Round 12
// 449.331 us; speedup vs baseline: 2.6190x; 1.0127x over previous
//
#include <hip/hip_runtime.h>
#include <hip/hip_bf16.h>

#define N_NODES 50000
#define N_EDGES 1600000
#define HEADS 8
#define HDIM 16
#define D1 128   // HEADS*HDIM
#define NEG_SLOPE 0.2f
#define SCAN_BLKS 196  // ceil(50000/256)
#define RTILES 3125    // 50000/16

typedef short short8 __attribute__((ext_vector_type(8)));
typedef float f32x4 __attribute__((ext_vector_type(4)));
typedef _Float16 half2v __attribute__((ext_vector_type(2)));

// ---- dtype helpers (isf32: 1 = buffers are fp32, 0 = bf16) ----
__device__ __forceinline__ float bf2f(ushort u) {
    union { unsigned u; float f; } x; x.u = ((unsigned)u) << 16; return x.f;
}
__device__ __forceinline__ ushort f2bf(float f) {
    union { float f; unsigned u; } x; x.f = f;
    unsigned r = x.u + 0x7FFF + ((x.u >> 16) & 1);   // RNE
    return (ushort)(r >> 16);
}
__device__ __forceinline__ float ldf(const void* p, size_t i, int isf32) {
    return isf32 ? ((const float*)p)[i] : bf2f(((const ushort*)p)[i]);
}
__device__ __forceinline__ void splitbf(float f, ushort& hi, ushort& lo) {
    unsigned u = __float_as_uint(f);
    unsigned uh = u & 0xFFFF0000u;
    hi = (ushort)(uh >> 16);
    lo = f2bf(f - __uint_as_float(uh));
}

// ---------------- workspace layout (bytes) ----------------
#define O_ROWPTR   0
#define O_DEG      200064
#define O_BSUM     400128
#define O_TMPSCAN  408320
#define O_FLAGS    608384
#define O_POS      608640
#define O_ESRC     7008640
#define O_W1HI     13408640      // 144x256 bf16
#define O_W1LO     13556096
#define O_W2HI     13703552      // 144x128 bf16
#define O_W2LO     13777280
#define O_B1F      13851008
#define O_B2F      13851520
#define O_FEATG    13852032      // fp16 [N][128] layer-1 features
#define O_EL       26652032
#define O_ER       28252032
#define O_FEATG2   29852032      // fp16 [N][128] layer-2 features
#define O_EL2      42652032
#define O_ER2      44252032

// ================= device helpers =================

__device__ __forceinline__ void detect_body(const ushort* w1, int* flags, int* sm) {
    int t = threadIdx.x;
    int cnt = 0;
    for (int i = t; i < 32768; i += 256) {
        int e = (w1[i] >> 7) & 0xFF;
        if (e >= 0xC8) cnt++;
    }
    sm[t] = cnt; __syncthreads();
    for (int off = 128; off > 0; off >>= 1) {
        if (t < off) sm[t] += sm[t + off];
        __syncthreads();
    }
    if (t == 0) flags[0] = (sm[0] > 0) ? 1 : 0;
}

// ---- phase A: zero deg (blocks 0..195) + dtype detect (block 196) ----
__global__ __launch_bounds__(256) void k_zerodetect(const ushort* __restrict__ w1,
                                                    int* __restrict__ deg, int* __restrict__ flags) {
    __shared__ int sm[256];
    int b = blockIdx.x;
    if (b < SCAN_BLKS) {
        int i = b * 256 + threadIdx.x;
        if (i < N_NODES) deg[i] = 0;
    } else {
        detect_body(w1, flags, sm);
    }
}

// W -> whi/wlo bf16 [144][K] transposed (rows 0..127 = W cols, 128..135 = W@al, 136..143 = W@ar)
__device__ __forceinline__ void wprep_elem(const void* W, const void* al, const void* ar,
                                           int K, int kshift, ushort* whi, ushort* wlo,
                                           int isf32, int idx) {
    if (idx >= 144 * K) return;
    int n = idx >> kshift, k = idx & (K - 1);
    float f;
    if (n < 128) {
        f = ldf(W, (size_t)k * 128 + n, isf32);
    } else if (n < 136) {
        int h = n - 128;
        f = 0.f;
#pragma unroll
        for (int d = 0; d < HDIM; ++d)
            f = fmaf(ldf(W, (size_t)k * 128 + h * 16 + d, isf32), ldf(al, h * 16 + d, isf32), f);
    } else {
        int h = n - 136;
        f = 0.f;
#pragma unroll
        for (int d = 0; d < HDIM; ++d)
            f = fmaf(ldf(W, (size_t)k * 128 + h * 16 + d, isf32), ldf(ar, h * 16 + d, isf32), f);
    }
    ushort hi = f2bf(f);
    wlo[n * K + k] = f2bf(f - bf2f(hi));
    whi[n * K + k] = hi;
}

// ---- phase B: edge count (blocks 0..1562) + weight prep (blocks 1563..1779) ----
__global__ __launch_bounds__(256) void k_countprep(const int4* __restrict__ dst4, int* __restrict__ deg,
                                                   int4* __restrict__ pos4,
                                                   const void* __restrict__ W1, const void* __restrict__ al1,
                                                   const void* __restrict__ ar1, const void* __restrict__ b1,
                                                   const void* __restrict__ W2, const void* __restrict__ al2,
                                                   const void* __restrict__ ar2, const void* __restrict__ b2,
                                                   ushort* __restrict__ w1hi, ushort* __restrict__ w1lo,
                                                   ushort* __restrict__ w2hi, ushort* __restrict__ w2lo,
                                                   float* __restrict__ b1f, float* __restrict__ b2f,
                                                   const int* __restrict__ flags) {
    int b = blockIdx.x, t = threadIdx.x;
    if (b < 1563) {
        int i = b * 256 + t;
        if (i < N_EDGES / 4) {
            int4 d = dst4[i];
            int4 p;
            p.x = atomicAdd(&deg[d.x], 1);
            p.y = atomicAdd(&deg[d.y], 1);
            p.z = atomicAdd(&deg[d.z], 1);
            p.w = atomicAdd(&deg[d.w], 1);
            pos4[i] = p;
        }
    } else {
        int isf32 = flags[0];
        int u = b - 1563;
        if (u < 144) {
            wprep_elem(W1, al1, ar1, 256, 8, w1hi, w1lo, isf32, u * 256 + t);
        } else if (u < 216) {
            wprep_elem(W2, al2, ar2, 128, 7, w2hi, w2lo, isf32, (u - 144) * 256 + t);
        } else {
            if (t < 128) b1f[t] = ldf(b1, t, isf32);
            else b2f[t - 128] = ldf(b2, t - 128, isf32);
        }
    }
}

__global__ __launch_bounds__(256) void k_scan1(const int* __restrict__ deg, int* __restrict__ tmp,
                                               int* __restrict__ bsum) {
    __shared__ int sm[256];
    int t = threadIdx.x;
    int i = blockIdx.x * 256 + t;
    int x = (i < N_NODES) ? deg[i] : 0;
    sm[t] = x; __syncthreads();
    for (int off = 1; off < 256; off <<= 1) {
        int v = (t >= off) ? sm[t - off] : 0;
        __syncthreads();
        sm[t] += v;
        __syncthreads();
    }
    if (i < N_NODES) tmp[i] = sm[t];
    if (t == 255) bsum[blockIdx.x] = sm[255];
}

__global__ __launch_bounds__(256) void k_scan23(const int* __restrict__ tmp, const int* __restrict__ bsum,
                                                int* __restrict__ rowptr) {
    __shared__ int sm[256];
    int t = threadIdx.x;
    int x = (t < SCAN_BLKS) ? bsum[t] : 0;
    sm[t] = x; __syncthreads();
    for (int off = 1; off < 256; off <<= 1) {
        int v = (t >= off) ? sm[t - off] : 0;
        __syncthreads();
        sm[t] += v;
        __syncthreads();
    }
    int boff = sm[blockIdx.x] - ((blockIdx.x < SCAN_BLKS) ? bsum[blockIdx.x] : 0);
    int i = blockIdx.x * 256 + t;
    if (i < N_NODES) rowptr[i + 1] = tmp[i] + boff;
    if (i == 0) rowptr[0] = 0;
}

// coalesced featg tile store via per-wave LDS region
__device__ __forceinline__ void store_tile(_Float16 (*sfe)[72], _Float16* featg,
                                           const f32x4* acc, int lane, int quad, int l16,
                                           int rowb0, int cbase) {
#pragma unroll
    for (int ci = 0; ci < 4; ++ci)
#pragma unroll
        for (int r = 0; r < 4; ++r)
            sfe[quad * 4 + r][ci * 16 + l16] = (_Float16)acc[ci][r];
    int rr = lane >> 3, ch = lane & 7;
#pragma unroll
    for (int s = 0; s < 2; ++s) {
        int row = s * 8 + rr;
        short8 v = *(const short8*)&sfe[row][ch * 8];
        *(short8*)(featg + (size_t)(rowb0 + row) * D1 + cbase * 16 + ch * 8) = v;
    }
}

// gemm1, 9 c-tiles per wave (A fetched ONCE into registers)
__device__ __forceinline__ void gemm1_wave9(const void* A, const ushort* Bhi, const ushort* Blo,
                                            _Float16* featg, float* el, float* er,
                                            int isf32, int rt, int lane, _Float16 (*sfe)[72]) {
    int quad = lane >> 4, l16 = lane & 15;
    const int K = 256;
    size_t a_off = (size_t)(rt * 16 + l16) * K + quad * 8;
    int rowb0 = rt * 16;

    short8 ahi[8], alo[8];
    if (isf32) {
        const float* ap = (const float*)A + a_off;
#pragma unroll
        for (int i = 0; i < 8; ++i) {
            f32x4 u0 = *(const f32x4*)(ap + 32 * i);
            f32x4 u1 = *(const f32x4*)(ap + 32 * i + 4);
            float a8[8] = {u0[0], u0[1], u0[2], u0[3], u1[0], u1[1], u1[2], u1[3]};
#pragma unroll
            for (int j = 0; j < 8; ++j) {
                ushort h, l;
                splitbf(a8[j], h, l);
                ahi[i][j] = (short)h; alo[i][j] = (short)l;
            }
        }
    } else {
        const ushort* ap = (const ushort*)A + a_off;
#pragma unroll
        for (int i = 0; i < 8; ++i) ahi[i] = *(const short8*)(ap + 32 * i);
    }

#pragma unroll
    for (int g = 0; g < 2; ++g) {
        f32x4 acc[4];
#pragma unroll
        for (int ci = 0; ci < 4; ++ci) acc[ci] = (f32x4){0.f, 0.f, 0.f, 0.f};
#pragma unroll
        for (int ci = 0; ci < 4; ++ci) {
            int c = g * 4 + ci;
            const ushort* bh = Bhi + (size_t)(c * 16 + l16) * K + quad * 8;
            if (isf32) {
                const ushort* bl = Blo + (size_t)(c * 16 + l16) * K + quad * 8;
#pragma unroll
                for (int k = 0; k < 8; ++k) {
                    short8 bh8 = *(const short8*)(bh + 32 * k);
                    short8 bl8 = *(const short8*)(bl + 32 * k);
                    acc[ci] = __builtin_amdgcn_mfma_f32_16x16x32_bf16(ahi[k], bh8, acc[ci], 0, 0, 0);
                    acc[ci] = __builtin_amdgcn_mfma_f32_16x16x32_bf16(ahi[k], bl8, acc[ci], 0, 0, 0);
                    acc[ci] = __builtin_amdgcn_mfma_f32_16x16x32_bf16(alo[k], bh8, acc[ci], 0, 0, 0);
                }
            } else {
#pragma unroll
                for (int k = 0; k < 8; ++k) {
                    short8 bh8 = *(const short8*)(bh + 32 * k);
                    acc[ci] = __builtin_amdgcn_mfma_f32_16x16x32_bf16(ahi[k], bh8, acc[ci], 0, 0, 0);
                }
            }
        }
        store_tile(sfe, featg, acc, lane, quad, l16, rowb0, g * 4);
    }

    // el/er fold tile (c=8)
    {
        const ushort* bh = Bhi + (size_t)(8 * 16 + l16) * K + quad * 8;
        const ushort* bl = Blo + (size_t)(8 * 16 + l16) * K + quad * 8;
        f32x4 a = {0.f, 0.f, 0.f, 0.f};
#pragma unroll
        for (int k = 0; k < 8; ++k) {
            short8 bh8 = *(const short8*)(bh + 32 * k);
            short8 bl8 = *(const short8*)(bl + 32 * k);
            a = __builtin_amdgcn_mfma_f32_16x16x32_bf16(ahi[k], bh8, a, 0, 0, 0);
            a = __builtin_amdgcn_mfma_f32_16x16x32_bf16(ahi[k], bl8, a, 0, 0, 0);
            if (isf32) a = __builtin_amdgcn_mfma_f32_16x16x32_bf16(alo[k], bh8, a, 0, 0, 0);
        }
#pragma unroll
        for (int r = 0; r < 4; ++r) {
            int row = rowb0 + quad * 4 + r;
            if (l16 < 8) el[row * 8 + l16] = a[r];
            else         er[row * 8 + (l16 - 8)] = a[r];
        }
    }
}

// ---- phase C: place (blocks 0..1562) + gemm1 (blocks 1563..2344) ----
__global__ __launch_bounds__(256) void k_placegemm1(const int4* __restrict__ src4, const int4* __restrict__ dst4,
                                                    const int* __restrict__ rowptr, const int4* __restrict__ pos4,
                                                    int* __restrict__ esrc,
                                                    const void* __restrict__ A,
                                                    const ushort* __restrict__ w1hi, const ushort* __restrict__ w1lo,
                                                    _Float16* __restrict__ featg,
                                                    float* __restrict__ el, float* __restrict__ er,
                                                    const int* __restrict__ flags) {
    __shared__ __align__(16) _Float16 sfe[4][16][72];
    int b = blockIdx.x, t = threadIdx.x;
    if (b < 1563) {
        int i = b * 256 + t;
        if (i < N_EDGES / 4) {
            int4 s = src4[i], d = dst4[i], p = pos4[i];
            esrc[rowptr[d.x] + p.x] = s.x;
            esrc[rowptr[d.y] + p.y] = s.y;
            esrc[rowptr[d.z] + p.z] = s.z;
            esrc[rowptr[d.w] + p.w] = s.w;
        }
    } else {
        int wave = t >> 6, lane = t & 63;
        int rt = (b - 1563) * 4 + wave;
        if (rt < RTILES)
            gemm1_wave9(A, w1hi, w1lo, featg, el, er, flags[0], rt, lane, sfe[wave]);
    }
}

// ---- shared gather core (batch-8 edges, one wave per node) ----
__device__ __forceinline__ void gather_core(const int* rowptr, const int* esrc, const half2v* featg,
                                            const float* el, const float* er, int v, int lane,
                                            float& acc0, float& acc1, float& den, int& deg) {
    int h8 = lane & 7;
    int esel = lane >> 3;
    float erv = er[v * 8 + h8];
    int beg = rowptr[v], end = rowptr[v + 1];
    deg = end - beg;
    acc0 = 0.f; acc1 = 0.f; den = 0.f;
    int jend = beg + (deg & ~7);
    for (int j = beg; j < jend; j += 8) {
        int sv = esrc[j + h8];
        int se = __shfl(sv, esel);
        float x = el[se * 8 + h8] + erv;
        x = x > 0.f ? x : NEG_SLOPE * x;
        float w = __expf(x);
        int s_[8];
#pragma unroll
        for (int e = 0; e < 8; ++e) s_[e] = __shfl(sv, e);
        half2v hh_[8];
#pragma unroll
        for (int e = 0; e < 8; ++e) hh_[e] = featg[(size_t)s_[e] * 64 + lane];
        float we_[8];
#pragma unroll
        for (int e = 0; e < 8; ++e) we_[e] = __shfl(w, e * 8 + esel);
#pragma unroll
        for (int e = 0; e < 8; ++e) {
            den += we_[e];
            acc0 = fmaf(we_[e], (float)hh_[e][0], acc0);
            acc1 = fmaf(we_[e], (float)hh_[e][1], acc1);
        }
    }
    int rem = deg & 7;
    if (rem) {
        int idx = jend + h8;
        if (idx >= end) idx = end - 1;
        int sv = esrc[idx];
        int se = __shfl(sv, esel);
        float x = el[se * 8 + h8] + erv;
        x = x > 0.f ? x : NEG_SLOPE * x;
        float w = __expf(x);
        for (int e = 0; e < rem; ++e) {
            float we = __shfl(w, e * 8 + esel);
            int s = __shfl(sv, e);
            half2v hh = featg[(size_t)s * 64 + lane];
            den += we;
            acc0 = fmaf(we, (float)hh[0], acc0);
            acc1 = fmaf(we, (float)hh[1], acc1);
        }
    }
}

// ---- phase D: agg layer 1 + fused MFMA dense (layer-2 transform) ----
// Block = 16 nodes (4 waves x 4 nodes). h rows (ELU'd, split-bf16) -> LDS 16x136 tiles,
// then block-level MFMA vs w2hi/w2lo (L2-resident): wave w -> c-tiles {w, w+4}; wave 0 also c=8.
__global__ __launch_bounds__(256) void k_agg1m(const int* __restrict__ rowptr, const int* __restrict__ esrc,
                                               const half2v* __restrict__ featg,
                                               const float* __restrict__ el, const float* __restrict__ er,
                                               const float* __restrict__ b1f,
                                               const ushort* __restrict__ w2hi, const ushort* __restrict__ w2lo,
                                               _Float16* __restrict__ featg2,
                                               float* __restrict__ el2, float* __restrict__ er2,
                                               const int* __restrict__ flags) {
    __shared__ __align__(16) ushort sh_hi[16][136];
    __shared__ __align__(16) ushort sh_lo[16][136];
    int isf32 = flags[0];
    int wave = threadIdx.x >> 6, lane = threadIdx.x & 63;
    int vb = blockIdx.x * 16;
    float2 bb = ((const float2*)b1f)[lane];
#pragma unroll
    for (int i = 0; i < 4; ++i) {
        int v = vb + wave * 4 + i;
        float acc0, acc1, den; int deg;
        gather_core(rowptr, esrc, featg, el, er, v, lane, acc0, acc1, den, deg);
        float inv = (deg > 0) ? 1.0f / den : 0.f;
        float r0 = fmaf(acc0, inv, bb.x);
        float r1 = fmaf(acc1, inv, bb.y);
        r0 = r0 > 0.f ? r0 : (__expf(r0) - 1.f);   // ELU
        r1 = r1 > 0.f ? r1 : (__expf(r1) - 1.f);
        ushort h0, l0, h1, l1;
        splitbf(r0, h0, l0);
        splitbf(r1, h1, l1);
        int m = wave * 4 + i;
        sh_hi[m][2 * lane] = h0; sh_hi[m][2 * lane + 1] = h1;
        sh_lo[m][2 * lane] = l0; sh_lo[m][2 * lane + 1] = l1;
    }
    __syncthreads();

    // MFMA epilogue: y = h @ W2ext (K=128)
    int quad = lane >> 4, l16 = lane & 15;
    const int K = 128;
    short8 ahi[4], alo[4];
#pragma unroll
    for (int k = 0; k < 4; ++k) {
        ahi[k] = *(const short8*)&sh_hi[l16][quad * 8 + 32 * k];
        alo[k] = *(const short8*)&sh_lo[l16][quad * 8 + 32 * k];
    }
    int ntile = (wave == 0) ? 3 : 2;
    for (int ti = 0; ti < ntile; ++ti) {
        int c = (ti == 2) ? 8 : wave + ti * 4;
        const ushort* bh = w2hi + (size_t)(c * 16 + l16) * K + quad * 8;
        const ushort* bl = w2lo + (size_t)(c * 16 + l16) * K + quad * 8;
        f32x4 a = {0.f, 0.f, 0.f, 0.f};
#pragma unroll
        for (int k = 0; k < 4; ++k) {
            short8 bh8 = *(const short8*)(bh + 32 * k);
            a = __builtin_amdgcn_mfma_f32_16x16x32_bf16(ahi[k], bh8, a, 0, 0, 0);
            a = __builtin_amdgcn_mfma_f32_16x16x32_bf16(alo[k], bh8, a, 0, 0, 0);
            if (c == 8 || isf32) {
                short8 bl8 = *(const short8*)(bl + 32 * k);
                a = __builtin_amdgcn_mfma_f32_16x16x32_bf16(ahi[k], bl8, a, 0, 0, 0);
            }
        }
        if (c < 8) {
#pragma unroll
            for (int r = 0; r < 4; ++r)
                featg2[(size_t)(vb + quad * 4 + r) * D1 + c * 16 + l16] = (_Float16)a[r];
        } else {
#pragma unroll
            for (int r = 0; r < 4; ++r) {
                int row = vb + quad * 4 + r;
                if (l16 < 8) el2[row * 8 + l16] = a[r];
                else         er2[row * 8 + (l16 - 8)] = a[r];
            }
        }
    }
}

// ---- phase E: agg layer 2 -> head-mean -> d_out ----
__global__ __launch_bounds__(256) void k_agg2(const int* __restrict__ rowptr, const int* __restrict__ esrc,
                                              const half2v* __restrict__ featg2,
                                              const float* __restrict__ el2, const float* __restrict__ er2,
                                              const float* __restrict__ b2f,
                                              void* __restrict__ out, const int* __restrict__ flags) {
    int wave = threadIdx.x >> 6, lane = threadIdx.x & 63;
    int v = blockIdx.x * 4 + wave;
    if (v >= N_NODES) return;
    float acc0, acc1, den; int deg;
    gather_core(rowptr, esrc, featg2, el2, er2, v, lane, acc0, acc1, den, deg);
    float inv = (deg > 0) ? 1.0f / den : 0.f;
    float2 bb = ((const float2*)b2f)[lane];
    float r0 = fmaf(acc0, inv, bb.x);
    float r1 = fmaf(acc1, inv, bb.y);
    for (int m = 8; m < 64; m <<= 1) {
        r0 += __shfl_xor(r0, m);
        r1 += __shfl_xor(r1, m);
    }
    if (lane < 8) {
        float v0 = r0 * 0.125f, v1 = r1 * 0.125f;
        if (flags[0]) {
            float2 st = {v0, v1};
            ((float2*)out)[(size_t)v * 8 + lane] = st;
        } else {
            unsigned pk = (unsigned)f2bf(v0) | ((unsigned)f2bf(v1) << 16);
            ((unsigned*)out)[(size_t)v * 8 + lane] = pk;
        }
    }
}

extern "C" void kernel_launch(void* const* d_in, const int* in_sizes, int n_in,
                              void* d_out, int out_size, void* d_ws, size_t ws_size,
                              hipStream_t stream) {
    const void* node_feat = d_in[0];
    const int4* src4 = (const int4*)d_in[1];
    const int4* dst4 = (const int4*)d_in[2];
    const void* W1 = d_in[3];
    const void* al1 = d_in[4];
    const void* ar1 = d_in[5];
    const void* b1 = d_in[6];
    const void* W2 = d_in[7];
    const void* al2 = d_in[8];
    const void* ar2 = d_in[9];
    const void* b2 = d_in[10];
    char* ws = (char*)d_ws;

    int* rowptr = (int*)(ws + O_ROWPTR);
    int* deg    = (int*)(ws + O_DEG);
    int* bsum   = (int*)(ws + O_BSUM);
    int* tmpsc  = (int*)(ws + O_TMPSCAN);
    int* flags  = (int*)(ws + O_FLAGS);
    int4* pos4  = (int4*)(ws + O_POS);
    int* esrc   = (int*)(ws + O_ESRC);
    ushort* w1hi = (ushort*)(ws + O_W1HI);
    ushort* w1lo = (ushort*)(ws + O_W1LO);
    ushort* w2hi = (ushort*)(ws + O_W2HI);
    ushort* w2lo = (ushort*)(ws + O_W2LO);
    float* b1f  = (float*)(ws + O_B1F);
    float* b2f  = (float*)(ws + O_B2F);
    _Float16* featg = (_Float16*)(ws + O_FEATG);
    float* el   = (float*)(ws + O_EL);
    float* er   = (float*)(ws + O_ER);
    _Float16* featg2 = (_Float16*)(ws + O_FEATG2);
    float* el2  = (float*)(ws + O_EL2);
    float* er2  = (float*)(ws + O_ER2);

    // A: zero deg + dtype detect
    k_zerodetect<<<SCAN_BLKS + 1, 256, 0, stream>>>((const ushort*)W1, deg, flags);
    // B: edge count (atomics) || weight prep (independent)
    k_countprep<<<1563 + 217, 256, 0, stream>>>(dst4, deg, pos4, W1, al1, ar1, b1,
                                                W2, al2, ar2, b2, w1hi, w1lo, w2hi, w2lo,
                                                b1f, b2f, flags);
    // scans
    k_scan1<<<SCAN_BLKS, 256, 0, stream>>>(deg, tmpsc, bsum);
    k_scan23<<<SCAN_BLKS, 256, 0, stream>>>(tmpsc, bsum, rowptr);
    // C: CSR place || gemm1 (A fetched once)
    k_placegemm1<<<1563 + 782, 256, 0, stream>>>(src4, dst4, rowptr, pos4, esrc,
                                                 node_feat, w1hi, w1lo, featg, el, er, flags);
    // D: agg layer 1 + fused MFMA dense -> featg2/el2/er2
    k_agg1m<<<N_NODES / 16, 256, 0, stream>>>(rowptr, esrc, (const half2v*)featg, el, er, b1f,
                                              w2hi, w2lo, featg2, el2, er2, flags);
    // E: agg layer 2 -> output
    k_agg2<<<(N_NODES + 3) / 4, 256, 0, stream>>>(rowptr, esrc, (const half2v*)featg2, el2, er2,
                                                  b2f, d_out, flags);
}